// Round 1
// baseline (2466.109 us; speedup 1.0000x reference)
//
#include <hip/hip_runtime.h>
#include <math.h>

#define NN 50000
#define NE 800000
#define DD 128
#define NEG_SLOPE 0.2f

// float atomic max via sign-split int/uint trick (m initialized to -inf).
__device__ __forceinline__ void atomic_max_float(float* addr, float val) {
  if (val >= 0.f)
    atomicMax((int*)addr, __float_as_int(val));
  else
    atomicMin((unsigned int*)addr, __float_as_uint(val));
}

// ---- GEMM: z = x @ W  (N x 128 @ 128 x 128), fused el = z.al, er = z.ar ----
// 256 threads/block, 64 rows/block; thread computes 8 rows x 4 cols.
// x tile staged in LDS (broadcast reads, conflict-free); W streamed (64 KB, L2-resident).
__global__ __launch_bounds__(256) void gemm_elr(
    const float* __restrict__ x, const float* __restrict__ W,
    const float* __restrict__ al, const float* __restrict__ ar,
    float* __restrict__ z, float* __restrict__ el, float* __restrict__ er) {
  __shared__ float4 sx4[64 * 32];
  const int t = threadIdx.x;
  const int row0 = blockIdx.x * 64;

  for (int i = t; i < 64 * 32; i += 256) {
    int r = row0 + (i >> 5);
    float4 v = make_float4(0.f, 0.f, 0.f, 0.f);
    if (r < NN) v = ((const float4*)x)[r * 32 + (i & 31)];
    sx4[i] = v;
  }
  __syncthreads();

  const int cg = t & 31;   // column group: cols c0..c0+3
  const int rg = t >> 5;   // row group: rows rg*8..rg*8+7
  const int c0 = cg * 4;

  float4 acc[8];
#pragma unroll
  for (int r = 0; r < 8; r++) acc[r] = make_float4(0.f, 0.f, 0.f, 0.f);

  for (int k4 = 0; k4 < 32; k4++) {
    float4 xa[8];
#pragma unroll
    for (int r = 0; r < 8; r++) xa[r] = sx4[(rg * 8 + r) * 32 + k4];  // lane-uniform -> LDS broadcast
#pragma unroll
    for (int kk = 0; kk < 4; kk++) {
      float4 wv = *(const float4*)(W + (k4 * 4 + kk) * DD + c0);
#pragma unroll
      for (int r = 0; r < 8; r++) {
        float xv = (kk == 0) ? xa[r].x : (kk == 1) ? xa[r].y : (kk == 2) ? xa[r].z : xa[r].w;
        acc[r].x += xv * wv.x;
        acc[r].y += xv * wv.y;
        acc[r].z += xv * wv.z;
        acc[r].w += xv * wv.w;
      }
    }
  }

  float4 alv = *(const float4*)(al + c0);
  float4 arv = *(const float4*)(ar + c0);
#pragma unroll
  for (int r = 0; r < 8; r++) {
    int row = row0 + rg * 8 + r;
    float pl = acc[r].x * alv.x + acc[r].y * alv.y + acc[r].z * alv.z + acc[r].w * alv.w;
    float pr = acc[r].x * arv.x + acc[r].y * arv.y + acc[r].z * arv.z + acc[r].w * arv.w;
    // reduce over the 32 col-group lanes (xor masks <=16 stay within each 32-lane half)
#pragma unroll
    for (int off = 16; off; off >>= 1) {
      pl += __shfl_xor(pl, off, 64);
      pr += __shfl_xor(pr, off, 64);
    }
    if (row < NN) {
      *(float4*)(z + row * DD + c0) = acc[r];
      if (cg == 0) { el[row] = pl; er[row] = pr; }
    }
  }
}

__global__ __launch_bounds__(256) void init_ms(float* __restrict__ m, float* __restrict__ s) {
  int i = blockIdx.x * 256 + threadIdx.x;
  if (i < NN) { m[i] = -INFINITY; s[i] = 0.f; }
}

__global__ __launch_bounds__(256) void edge_max(
    const int* __restrict__ src, const int* __restrict__ dst,
    const float* __restrict__ el, const float* __restrict__ er,
    float* __restrict__ e_buf, float* __restrict__ m) {
  int i = blockIdx.x * 256 + threadIdx.x;
  if (i >= NE) return;
  float e = el[src[i]] + er[dst[i]];
  e = (e > 0.f) ? e : NEG_SLOPE * e;
  e_buf[i] = e;
  atomic_max_float(&m[dst[i]], e);
}

__global__ __launch_bounds__(256) void edge_exp(
    const int* __restrict__ dst, const float* __restrict__ e_buf,
    const float* __restrict__ m, float* __restrict__ ex_buf, float* __restrict__ s) {
  int i = blockIdx.x * 256 + threadIdx.x;
  if (i >= NE) return;
  int d = dst[i];
  float ex = expf(e_buf[i] - m[d]);
  ex_buf[i] = ex;
  atomicAdd(&s[d], ex);
}

// out[dst,:] += (ex/s[dst]) * z[src,:] ; 64 threads per edge, 2 dims (float2) per thread.
__global__ __launch_bounds__(256) void agg(
    const int* __restrict__ src, const int* __restrict__ dst,
    const float* __restrict__ ex_buf, const float* __restrict__ s,
    const float* __restrict__ z, float* __restrict__ acc) {
  long long idx = (long long)blockIdx.x * 256 + threadIdx.x;
  int eid = (int)(idx >> 6);
  if (eid >= NE) return;
  int d2 = ((int)idx & 63) * 2;
  int sn = src[eid], dn = dst[eid];
  float alpha = ex_buf[eid] / s[dn];
  float2 zv = *(const float2*)(z + sn * DD + d2);
  atomicAdd(acc + dn * DD + d2, alpha * zv.x);
  atomicAdd(acc + dn * DD + d2 + 1, alpha * zv.y);
}

__global__ __launch_bounds__(256) void bias_relu(
    const float* __restrict__ acc, const float* __restrict__ b, float* __restrict__ out) {
  int i = blockIdx.x * 256 + threadIdx.x;
  if (i < NN * DD) {
    float v = acc[i] + b[i & (DD - 1)];
    out[i] = v > 0.f ? v : 0.f;
  }
}

extern "C" void kernel_launch(void* const* d_in, const int* in_sizes, int n_in,
                              void* d_out, int out_size, void* d_ws, size_t ws_size,
                              hipStream_t stream) {
  const float* f   = (const float*)d_in[0];
  const int*   src = (const int*)d_in[1];
  const int*   dst = (const int*)d_in[2];
  const float* W[3]  = {(const float*)d_in[3], (const float*)d_in[7],  (const float*)d_in[11]};
  const float* al[3] = {(const float*)d_in[4], (const float*)d_in[8],  (const float*)d_in[12]};
  const float* ar[3] = {(const float*)d_in[5], (const float*)d_in[9],  (const float*)d_in[13]};
  const float* bb[3] = {(const float*)d_in[6], (const float*)d_in[10], (const float*)d_in[14]};

  // workspace layout (floats): z | acc | h | el | er | m | s | e_buf | ex_buf  (~84 MB)
  float* ws     = (float*)d_ws;
  float* zbuf   = ws;
  float* accb   = zbuf + (size_t)NN * DD;
  float* hbuf   = accb + (size_t)NN * DD;
  float* el     = hbuf + (size_t)NN * DD;
  float* er     = el + NN;
  float* mb     = er + NN;
  float* sb     = mb + NN;
  float* e_buf  = sb + NN;
  float* ex_buf = e_buf + NE;

  const float* x = f;
  for (int L = 0; L < 3; L++) {
    float* out = (L == 2) ? (float*)d_out : hbuf;
    hipMemsetAsync(accb, 0, (size_t)NN * DD * sizeof(float), stream);
    init_ms<<<(NN + 255) / 256, 256, 0, stream>>>(mb, sb);
    gemm_elr<<<(NN + 63) / 64, 256, 0, stream>>>(x, W[L], al[L], ar[L], zbuf, el, er);
    edge_max<<<(NE + 255) / 256, 256, 0, stream>>>(src, dst, el, er, e_buf, mb);
    edge_exp<<<(NE + 255) / 256, 256, 0, stream>>>(dst, e_buf, mb, ex_buf, sb);
    agg<<<((long long)NE * 64 + 255) / 256, 256, 0, stream>>>(src, dst, ex_buf, sb, zbuf, accb);
    bias_relu<<<(NN * DD + 255) / 256, 256, 0, stream>>>(accb, bb[L], out);
    x = out;
  }
}

// Round 2
// 652.655 us; speedup vs baseline: 3.7786x; 3.7786x over previous
//
#include <hip/hip_runtime.h>
#include <math.h>

#define NN 50000
#define NE 800000
#define DD 128
#define NEG_SLOPE 0.2f

// ---- GEMM: z = x @ W  (N x 128 @ 128 x 128), fused el = z.al, er = z.ar ----
__global__ __launch_bounds__(256) void gemm_elr(
    const float* __restrict__ x, const float* __restrict__ W,
    const float* __restrict__ al, const float* __restrict__ ar,
    float* __restrict__ z, float* __restrict__ el, float* __restrict__ er) {
  __shared__ float4 sx4[64 * 32];
  const int t = threadIdx.x;
  const int row0 = blockIdx.x * 64;

  for (int i = t; i < 64 * 32; i += 256) {
    int r = row0 + (i >> 5);
    float4 v = make_float4(0.f, 0.f, 0.f, 0.f);
    if (r < NN) v = ((const float4*)x)[r * 32 + (i & 31)];
    sx4[i] = v;
  }
  __syncthreads();

  const int cg = t & 31;   // column group: cols c0..c0+3
  const int rg = t >> 5;   // row group: rows rg*8..rg*8+7
  const int c0 = cg * 4;

  float4 acc[8];
#pragma unroll
  for (int r = 0; r < 8; r++) acc[r] = make_float4(0.f, 0.f, 0.f, 0.f);

  for (int k4 = 0; k4 < 32; k4++) {
    float4 xa[8];
#pragma unroll
    for (int r = 0; r < 8; r++) xa[r] = sx4[(rg * 8 + r) * 32 + k4];
#pragma unroll
    for (int kk = 0; kk < 4; kk++) {
      float4 wv = *(const float4*)(W + (k4 * 4 + kk) * DD + c0);
#pragma unroll
      for (int r = 0; r < 8; r++) {
        float xv = (kk == 0) ? xa[r].x : (kk == 1) ? xa[r].y : (kk == 2) ? xa[r].z : xa[r].w;
        acc[r].x += xv * wv.x;
        acc[r].y += xv * wv.y;
        acc[r].z += xv * wv.z;
        acc[r].w += xv * wv.w;
      }
    }
  }

  float4 alv = *(const float4*)(al + c0);
  float4 arv = *(const float4*)(ar + c0);
#pragma unroll
  for (int r = 0; r < 8; r++) {
    int row = row0 + rg * 8 + r;
    float pl = acc[r].x * alv.x + acc[r].y * alv.y + acc[r].z * alv.z + acc[r].w * alv.w;
    float pr = acc[r].x * arv.x + acc[r].y * arv.y + acc[r].z * arv.z + acc[r].w * arv.w;
#pragma unroll
    for (int off = 16; off; off >>= 1) {
      pl += __shfl_xor(pl, off, 64);
      pr += __shfl_xor(pr, off, 64);
    }
    if (row < NN) {
      *(float4*)(z + row * DD + c0) = acc[r];
      if (cg == 0) { el[row] = pl; er[row] = pr; }
    }
  }
}

// ---- CSR build (once per launch, reused by all 3 layers) ----
__global__ __launch_bounds__(256) void hist(const int* __restrict__ dst, int* __restrict__ deg) {
  int i = blockIdx.x * 256 + threadIdx.x;
  if (i < NE) atomicAdd(&deg[dst[i]], 1);
}

// Single-block exclusive scan of deg[0..NN) -> rowptr[0..NN]
__global__ __launch_bounds__(1024) void scan_rowptr(const int* __restrict__ deg, int* __restrict__ rowptr) {
  __shared__ int psum[1024];
  const int t = threadIdx.x;
  const int CH = (NN + 1023) / 1024;  // 49
  int begin = t * CH;
  int end = begin + CH; if (end > NN) end = NN;
  int s = 0;
  for (int i = begin; i < end; i++) s += deg[i];
  psum[t] = s;
  __syncthreads();
  for (int off = 1; off < 1024; off <<= 1) {
    int v = (t >= off) ? psum[t - off] : 0;
    __syncthreads();
    psum[t] += v;
    __syncthreads();
  }
  int running = psum[t] - s;  // exclusive base
  for (int i = begin; i < end; i++) { rowptr[i] = running; running += deg[i]; }
  if (t == 1023) rowptr[NN] = psum[1023];
}

__global__ __launch_bounds__(256) void scatter(
    const int* __restrict__ src, const int* __restrict__ dst,
    const int* __restrict__ rowptr, int* __restrict__ cnt, int* __restrict__ csr_src) {
  int i = blockIdx.x * 256 + threadIdx.x;
  if (i >= NE) return;
  int d = dst[i];
  int pos = rowptr[d] + atomicAdd(&cnt[d], 1);
  csr_src[pos] = src[i];
}

// ---- Fused per-dst softmax + aggregation + bias + ReLU. One wave per node. ----
__global__ __launch_bounds__(256) void gat_agg(
    const int* __restrict__ rowptr, const int* __restrict__ csr_src,
    const float* __restrict__ el, const float* __restrict__ er,
    const float* __restrict__ z, const float* __restrict__ b,
    float* __restrict__ out) {
  int node = (int)((blockIdx.x * 256 + threadIdx.x) >> 6);
  int lane = threadIdx.x & 63;
  if (node >= NN) return;
  int beg = rowptr[node], end = rowptr[node + 1];
  float erd = er[node];

  // pass 1a: segment max (lane-parallel over edges)
  float m = -INFINITY;
  for (int j = beg + lane; j < end; j += 64) {
    float e = el[csr_src[j]] + erd;
    e = (e > 0.f) ? e : NEG_SLOPE * e;
    m = fmaxf(m, e);
  }
#pragma unroll
  for (int off = 32; off; off >>= 1) m = fmaxf(m, __shfl_xor(m, off, 64));

  // pass 1b: exp-sum
  float s = 0.f;
  for (int j = beg + lane; j < end; j += 64) {
    float e = el[csr_src[j]] + erd;
    e = (e > 0.f) ? e : NEG_SLOPE * e;
    s += expf(e - m);
  }
#pragma unroll
  for (int off = 32; off; off >>= 1) s += __shfl_xor(s, off, 64);
  float inv_s = (end > beg) ? 1.f / s : 0.f;

  // pass 2: weighted aggregation; lane owns dims 2*lane, 2*lane+1
  float2 acc = make_float2(0.f, 0.f);
  for (int j = beg; j < end; j++) {
    int sn = csr_src[j];                       // wave-uniform broadcast load
    float e = el[sn] + erd;
    e = (e > 0.f) ? e : NEG_SLOPE * e;
    float alpha = expf(e - m) * inv_s;
    float2 zv = *(const float2*)(z + (size_t)sn * DD + lane * 2);
    acc.x += alpha * zv.x;
    acc.y += alpha * zv.y;
  }
  float2 bv = *(const float2*)(b + lane * 2);
  float ox = acc.x + bv.x, oy = acc.y + bv.y;
  float2 o = make_float2(ox > 0.f ? ox : 0.f, oy > 0.f ? oy : 0.f);
  *(float2*)(out + (size_t)node * DD + lane * 2) = o;
}

extern "C" void kernel_launch(void* const* d_in, const int* in_sizes, int n_in,
                              void* d_out, int out_size, void* d_ws, size_t ws_size,
                              hipStream_t stream) {
  const float* f   = (const float*)d_in[0];
  const int*   src = (const int*)d_in[1];
  const int*   dst = (const int*)d_in[2];
  const float* W[3]  = {(const float*)d_in[3], (const float*)d_in[7],  (const float*)d_in[11]};
  const float* al[3] = {(const float*)d_in[4], (const float*)d_in[8],  (const float*)d_in[12]};
  const float* ar[3] = {(const float*)d_in[5], (const float*)d_in[9],  (const float*)d_in[13]};
  const float* bb[3] = {(const float*)d_in[6], (const float*)d_in[10], (const float*)d_in[14]};

  // workspace layout: z | h | el | er (floats) then deg | cnt | rowptr | csr_src (ints)
  float* ws    = (float*)d_ws;
  float* zbuf  = ws;
  float* hbuf  = zbuf + (size_t)NN * DD;
  float* el    = hbuf + (size_t)NN * DD;
  float* er    = el + NN;
  int* deg     = (int*)(er + NN);
  int* cnt     = deg + NN;
  int* rowptr  = cnt + NN;
  int* csr_src = rowptr + (NN + 1);

  // ---- CSR build (graph fixed across layers) ----
  hipMemsetAsync(deg, 0, NN * sizeof(int), stream);
  hipMemsetAsync(cnt, 0, NN * sizeof(int), stream);
  hist<<<(NE + 255) / 256, 256, 0, stream>>>(dst, deg);
  scan_rowptr<<<1, 1024, 0, stream>>>(deg, rowptr);
  scatter<<<(NE + 255) / 256, 256, 0, stream>>>(src, dst, rowptr, cnt, csr_src);

  const float* x = f;
  for (int L = 0; L < 3; L++) {
    float* out = (L == 2) ? (float*)d_out : hbuf;
    gemm_elr<<<(NN + 63) / 64, 256, 0, stream>>>(x, W[L], al[L], ar[L], zbuf, el, er);
    gat_agg<<<(NN * 64 + 255) / 256, 256, 0, stream>>>(rowptr, csr_src, el, er, zbuf, bb[L], out);
    x = out;
  }
}

// Round 3
// 486.871 us; speedup vs baseline: 5.0652x; 1.3405x over previous
//
#include <hip/hip_runtime.h>
#include <math.h>

#define NN 50000
#define NE 800000
#define DD 128
#define NEG_SLOPE 0.2f
#define MWAVES (NN / 16)   // 3125 waves, exact

typedef short frag8 __attribute__((ext_vector_type(8)));
typedef float f32x4 __attribute__((ext_vector_type(4)));

// round-to-nearest-even fp32 -> bf16 (as ushort)
__device__ __forceinline__ unsigned bf16_rne(float x) {
  unsigned u = __float_as_uint(x);
  return (u + 0x7FFFu + ((u >> 16) & 1u)) >> 16;
}

// ---- W pre-split + pre-swizzle into MFMA B-fragment order ----
// Layout: Wh[((kt*8+nt)*64 + lane)*8 + j] = bf16_hi( W[kt*32 + (lane>>4)*8 + j][nt*16 + (lane&15)] )
__global__ __launch_bounds__(256) void wsplit(const float* __restrict__ W,
                                              short* __restrict__ Wh, short* __restrict__ Wl) {
  int idx = blockIdx.x * 256 + threadIdx.x;           // 0..16383
  int j = idx & 7;
  int lane = (idx >> 3) & 63;
  int tile = idx >> 9;                                // kt*8 + nt
  int nt = tile & 7, kt = tile >> 3;
  int k = kt * 32 + (lane >> 4) * 8 + j;
  int n = nt * 16 + (lane & 15);
  float x = W[k * DD + n];
  unsigned hu = bf16_rne(x);
  float hf = __uint_as_float(hu << 16);
  unsigned lu = bf16_rne(x - hf);
  Wh[idx] = (short)hu;
  Wl[idx] = (short)lu;
}

// ---- GEMM z = x@W via split-bf16 MFMA, fused el = z.al, er = z.ar ----
// One wave: 16 rows x 128 cols. 4 k-tiles x 8 n-tiles x 3 split-products = 96 MFMAs.
__global__ __launch_bounds__(256) void gemm_mfma(
    const float* __restrict__ x, const short* __restrict__ Wh, const short* __restrict__ Wl,
    const float* __restrict__ al, const float* __restrict__ ar,
    float* __restrict__ z, float* __restrict__ el, float* __restrict__ er) {
  int wid = blockIdx.x * 4 + (threadIdx.x >> 6);
  if (wid >= MWAVES) return;
  int lane = threadIdx.x & 63;
  int m = lane & 15, quad = lane >> 4;
  int R0 = wid * 16;

  f32x4 acc[8];
#pragma unroll
  for (int t = 0; t < 8; t++) acc[t] = (f32x4)(0.f);

#pragma unroll
  for (int kt = 0; kt < 4; kt++) {
    // A fragment: rows R0+m, k = kt*32 + quad*8 + j
    const float* xp = x + (size_t)(R0 + m) * DD + kt * 32 + quad * 8;
    float xv[8];
    *(float4*)(xv) = *(const float4*)xp;
    *(float4*)(xv + 4) = *(const float4*)(xp + 4);
    frag8 ah, alo;
#pragma unroll
    for (int j = 0; j < 8; j++) {
      unsigned hu = bf16_rne(xv[j]);
      float hf = __uint_as_float(hu << 16);
      unsigned lu = bf16_rne(xv[j] - hf);
      ah[j] = (short)hu;
      alo[j] = (short)lu;
    }
#pragma unroll
    for (int nt = 0; nt < 8; nt++) {
      int base = ((kt * 8 + nt) * 64 + lane) * 8;
      frag8 bh = *(const frag8*)(Wh + base);
      frag8 bl = *(const frag8*)(Wl + base);
      acc[nt] = __builtin_amdgcn_mfma_f32_16x16x32_bf16(alo, bh, acc[nt], 0, 0, 0);
      acc[nt] = __builtin_amdgcn_mfma_f32_16x16x32_bf16(ah, bl, acc[nt], 0, 0, 0);
      acc[nt] = __builtin_amdgcn_mfma_f32_16x16x32_bf16(ah, bh, acc[nt], 0, 0, 0);
    }
  }

  // Epilogue: lane holds D[row = quad*4 + r][col = nt*16 + m]
  float alv[8], arv[8];
#pragma unroll
  for (int nt = 0; nt < 8; nt++) { alv[nt] = al[nt * 16 + m]; arv[nt] = ar[nt * 16 + m]; }
#pragma unroll
  for (int r = 0; r < 4; r++) {
    float pl = 0.f, pr = 0.f;
#pragma unroll
    for (int nt = 0; nt < 8; nt++) { pl += acc[nt][r] * alv[nt]; pr += acc[nt][r] * arv[nt]; }
#pragma unroll
    for (int off = 8; off; off >>= 1) {  // reduce over m (bits 0..3); quad bits untouched
      pl += __shfl_xor(pl, off, 64);
      pr += __shfl_xor(pr, off, 64);
    }
    int row = R0 + quad * 4 + r;
    if (m == 0) { el[row] = pl; er[row] = pr; }
#pragma unroll
    for (int nt = 0; nt < 8; nt++) z[(size_t)row * DD + nt * 16 + m] = acc[nt][r];
  }
}

// ---- CSR build (once per launch, reused by all 3 layers) ----
__global__ __launch_bounds__(256) void hist(const int* __restrict__ dst, int* __restrict__ deg) {
  int i = blockIdx.x * 256 + threadIdx.x;
  if (i < NE) atomicAdd(&deg[dst[i]], 1);
}

__global__ __launch_bounds__(1024) void scan_rowptr(const int* __restrict__ deg, int* __restrict__ rowptr) {
  __shared__ int psum[1024];
  const int t = threadIdx.x;
  const int CH = (NN + 1023) / 1024;
  int begin = t * CH;
  int end = begin + CH; if (end > NN) end = NN;
  int s = 0;
  for (int i = begin; i < end; i++) s += deg[i];
  psum[t] = s;
  __syncthreads();
  for (int off = 1; off < 1024; off <<= 1) {
    int v = (t >= off) ? psum[t - off] : 0;
    __syncthreads();
    psum[t] += v;
    __syncthreads();
  }
  int running = psum[t] - s;
  for (int i = begin; i < end; i++) { rowptr[i] = running; running += deg[i]; }
  if (t == 1023) rowptr[NN] = psum[1023];
}

__global__ __launch_bounds__(256) void scatter(
    const int* __restrict__ src, const int* __restrict__ dst,
    const int* __restrict__ rowptr, int* __restrict__ cnt, int* __restrict__ csr_src) {
  int i = blockIdx.x * 256 + threadIdx.x;
  if (i >= NE) return;
  int d = dst[i];
  int pos = rowptr[d] + atomicAdd(&cnt[d], 1);
  csr_src[pos] = src[i];
}

// ---- Fused softmax + aggregation + bias + ReLU. One wave per node. ----
// Per-lane edge weights cached in registers; serial loop = shfl + load + FMA, unrolled x4.
__global__ __launch_bounds__(256) void gat_agg(
    const int* __restrict__ rowptr, const int* __restrict__ csr_src,
    const float* __restrict__ el, const float* __restrict__ er,
    const float* __restrict__ z, const float* __restrict__ b,
    float* __restrict__ out) {
  int node = (int)((blockIdx.x * 256 + threadIdx.x) >> 6);
  int lane = threadIdx.x & 63;
  if (node >= NN) return;
  int beg = rowptr[node], end = rowptr[node + 1];
  float erd = er[node];

  // segment max (lane-parallel)
  float m = -INFINITY;
  for (int base = beg; base < end; base += 64) {
    int j = base + lane;
    if (j < end) {
      float e = el[csr_src[j]] + erd;
      e = (e > 0.f) ? e : NEG_SLOPE * e;
      m = fmaxf(m, e);
    }
  }
#pragma unroll
  for (int off = 32; off; off >>= 1) m = fmaxf(m, __shfl_xor(m, off, 64));

  float2 acc = make_float2(0.f, 0.f);
  float ssum = 0.f;
  for (int base = beg; base < end; base += 64) {
    int j = base + lane;
    int sn = 0; float w = 0.f;
    if (j < end) {
      sn = csr_src[j];
      float e = el[sn] + erd;
      e = (e > 0.f) ? e : NEG_SLOPE * e;
      w = __expf(e - m);
    }
    ssum += w;
    int cnt = min(64, end - base);
    int jj = 0;
    for (; jj + 4 <= cnt; jj += 4) {
      float w0 = __shfl(w, jj, 64),     w1 = __shfl(w, jj + 1, 64);
      float w2 = __shfl(w, jj + 2, 64), w3 = __shfl(w, jj + 3, 64);
      int   s0 = __shfl(sn, jj, 64),     s1 = __shfl(sn, jj + 1, 64);
      int   s2 = __shfl(sn, jj + 2, 64), s3 = __shfl(sn, jj + 3, 64);
      float2 z0 = *(const float2*)(z + (size_t)s0 * DD + lane * 2);
      float2 z1 = *(const float2*)(z + (size_t)s1 * DD + lane * 2);
      float2 z2 = *(const float2*)(z + (size_t)s2 * DD + lane * 2);
      float2 z3 = *(const float2*)(z + (size_t)s3 * DD + lane * 2);
      acc.x += w0 * z0.x; acc.y += w0 * z0.y;
      acc.x += w1 * z1.x; acc.y += w1 * z1.y;
      acc.x += w2 * z2.x; acc.y += w2 * z2.y;
      acc.x += w3 * z3.x; acc.y += w3 * z3.y;
    }
    for (; jj < cnt; jj++) {
      float wj = __shfl(w, jj, 64);
      int snj = __shfl(sn, jj, 64);
      float2 zv = *(const float2*)(z + (size_t)snj * DD + lane * 2);
      acc.x += wj * zv.x; acc.y += wj * zv.y;
    }
  }
#pragma unroll
  for (int off = 32; off; off >>= 1) ssum += __shfl_xor(ssum, off, 64);
  float inv_s = (end > beg) ? 1.f / ssum : 0.f;

  float2 bv = *(const float2*)(b + lane * 2);
  float ox = acc.x * inv_s + bv.x, oy = acc.y * inv_s + bv.y;
  *(float2*)(out + (size_t)node * DD + lane * 2) = make_float2(ox > 0.f ? ox : 0.f, oy > 0.f ? oy : 0.f);
}

extern "C" void kernel_launch(void* const* d_in, const int* in_sizes, int n_in,
                              void* d_out, int out_size, void* d_ws, size_t ws_size,
                              hipStream_t stream) {
  const float* f   = (const float*)d_in[0];
  const int*   src = (const int*)d_in[1];
  const int*   dst = (const int*)d_in[2];
  const float* W[3]  = {(const float*)d_in[3], (const float*)d_in[7],  (const float*)d_in[11]};
  const float* al[3] = {(const float*)d_in[4], (const float*)d_in[8],  (const float*)d_in[12]};
  const float* ar[3] = {(const float*)d_in[5], (const float*)d_in[9],  (const float*)d_in[13]};
  const float* bb[3] = {(const float*)d_in[6], (const float*)d_in[10], (const float*)d_in[14]};

  // ws layout: Wh[3] | Wl[3] (shorts, 16B-aligned at base) | z | h | el | er (floats) | ints
  short* Wh3 = (short*)d_ws;                 // 3 * 16384 shorts
  short* Wl3 = Wh3 + 3 * 16384;
  float* zbuf = (float*)(Wl3 + 3 * 16384);
  float* hbuf = zbuf + (size_t)NN * DD;
  float* el   = hbuf + (size_t)NN * DD;
  float* er   = el + NN;
  int* deg    = (int*)(er + NN);
  int* cnt    = deg + NN;
  int* rowptr = cnt + NN;
  int* csr_src = rowptr + (NN + 1);

  // CSR build + weight split (graph & weights fixed across the launch)
  hipMemsetAsync(deg, 0, NN * sizeof(int), stream);
  hipMemsetAsync(cnt, 0, NN * sizeof(int), stream);
  hist<<<(NE + 255) / 256, 256, 0, stream>>>(dst, deg);
  scan_rowptr<<<1, 1024, 0, stream>>>(deg, rowptr);
  scatter<<<(NE + 255) / 256, 256, 0, stream>>>(src, dst, rowptr, cnt, csr_src);
  for (int L = 0; L < 3; L++)
    wsplit<<<16384 / 256, 256, 0, stream>>>(W[L], Wh3 + L * 16384, Wl3 + L * 16384);

  const float* x = f;
  for (int L = 0; L < 3; L++) {
    float* out = (L == 2) ? (float*)d_out : hbuf;
    gemm_mfma<<<(MWAVES + 3) / 4, 256, 0, stream>>>(x, Wh3 + L * 16384, Wl3 + L * 16384,
                                                    al[L], ar[L], zbuf, el, er);
    gat_agg<<<(NN * 64) / 256, 256, 0, stream>>>(rowptr, csr_src, el, er, zbuf, bb[L], out);
    x = out;
  }
}

// Round 4
// 414.085 us; speedup vs baseline: 5.9556x; 1.1758x over previous
//
#include <hip/hip_runtime.h>
#include <math.h>

#define NN 50000
#define NE 800000
#define DD 128
#define NEG_SLOPE 0.2f
#define MWAVES (NN / 16)          // 3125 waves, exact
#define NB ((NN + 255) / 256)     // 196 scan blocks

typedef short frag8 __attribute__((ext_vector_type(8)));
typedef float f32x4 __attribute__((ext_vector_type(4)));

// round-to-nearest-even fp32 -> bf16 (as ushort)
__device__ __forceinline__ unsigned bf16_rne(float x) {
  unsigned u = __float_as_uint(x);
  return (u + 0x7FFFu + ((u >> 16) & 1u)) >> 16;
}

// ---- W pre-split + pre-swizzle into MFMA B-fragment order ----
__global__ __launch_bounds__(256) void wsplit(const float* __restrict__ W,
                                              short* __restrict__ Wh, short* __restrict__ Wl) {
  int idx = blockIdx.x * 256 + threadIdx.x;           // 0..16383
  int j = idx & 7;
  int lane = (idx >> 3) & 63;
  int tile = idx >> 9;                                // kt*8 + nt
  int nt = tile & 7, kt = tile >> 3;
  int k = kt * 32 + (lane >> 4) * 8 + j;
  int n = nt * 16 + (lane & 15);
  float x = W[k * DD + n];
  unsigned hu = bf16_rne(x);
  float hf = __uint_as_float(hu << 16);
  unsigned lu = bf16_rne(x - hf);
  Wh[idx] = (short)hu;
  Wl[idx] = (short)lu;
}

// ---- GEMM z = x@W via split-bf16 MFMA, fused el = z.al, er = z.ar ----
__global__ __launch_bounds__(256) void gemm_mfma(
    const float* __restrict__ x, const short* __restrict__ Wh, const short* __restrict__ Wl,
    const float* __restrict__ al, const float* __restrict__ ar,
    float* __restrict__ z, float* __restrict__ el, float* __restrict__ er) {
  int wid = blockIdx.x * 4 + (threadIdx.x >> 6);
  if (wid >= MWAVES) return;
  int lane = threadIdx.x & 63;
  int m = lane & 15, quad = lane >> 4;
  int R0 = wid * 16;

  f32x4 acc[8];
#pragma unroll
  for (int t = 0; t < 8; t++) acc[t] = (f32x4)(0.f);

#pragma unroll
  for (int kt = 0; kt < 4; kt++) {
    const float* xp = x + (size_t)(R0 + m) * DD + kt * 32 + quad * 8;
    float xv[8];
    *(float4*)(xv) = *(const float4*)xp;
    *(float4*)(xv + 4) = *(const float4*)(xp + 4);
    frag8 ah, alo;
#pragma unroll
    for (int j = 0; j < 8; j++) {
      unsigned hu = bf16_rne(xv[j]);
      float hf = __uint_as_float(hu << 16);
      unsigned lu = bf16_rne(xv[j] - hf);
      ah[j] = (short)hu;
      alo[j] = (short)lu;
    }
#pragma unroll
    for (int nt = 0; nt < 8; nt++) {
      int base = ((kt * 8 + nt) * 64 + lane) * 8;
      frag8 bh = *(const frag8*)(Wh + base);
      frag8 bl = *(const frag8*)(Wl + base);
      acc[nt] = __builtin_amdgcn_mfma_f32_16x16x32_bf16(alo, bh, acc[nt], 0, 0, 0);
      acc[nt] = __builtin_amdgcn_mfma_f32_16x16x32_bf16(ah, bl, acc[nt], 0, 0, 0);
      acc[nt] = __builtin_amdgcn_mfma_f32_16x16x32_bf16(ah, bh, acc[nt], 0, 0, 0);
    }
  }

  float alv[8], arv[8];
#pragma unroll
  for (int nt = 0; nt < 8; nt++) { alv[nt] = al[nt * 16 + m]; arv[nt] = ar[nt * 16 + m]; }
#pragma unroll
  for (int r = 0; r < 4; r++) {
    float pl = 0.f, pr = 0.f;
#pragma unroll
    for (int nt = 0; nt < 8; nt++) { pl += acc[nt][r] * alv[nt]; pr += acc[nt][r] * arv[nt]; }
#pragma unroll
    for (int off = 8; off; off >>= 1) {
      pl += __shfl_xor(pl, off, 64);
      pr += __shfl_xor(pr, off, 64);
    }
    int row = R0 + quad * 4 + r;
    if (m == 0) { el[row] = pl; er[row] = pr; }
#pragma unroll
    for (int nt = 0; nt < 8; nt++) z[(size_t)row * DD + nt * 16 + m] = acc[nt][r];
  }
}

// ---- CSR build (once per launch, reused by all 3 layers) ----
__global__ __launch_bounds__(256) void hist(const int* __restrict__ dst, int* __restrict__ deg) {
  int i = blockIdx.x * 256 + threadIdx.x;
  if (i < NE) atomicAdd(&deg[dst[i]], 1);
}

// Phase A: per-block sums of deg (196 blocks x 256 elems)
__global__ __launch_bounds__(256) void block_sums(const int* __restrict__ deg, int* __restrict__ bsum) {
  int i = blockIdx.x * 256 + threadIdx.x;
  int v = (i < NN) ? deg[i] : 0;
#pragma unroll
  for (int off = 32; off; off >>= 1) v += __shfl_xor(v, off, 64);
  __shared__ int wsum[4];
  if ((threadIdx.x & 63) == 0) wsum[threadIdx.x >> 6] = v;
  __syncthreads();
  if (threadIdx.x == 0) bsum[blockIdx.x] = wsum[0] + wsum[1] + wsum[2] + wsum[3];
}

// Phase B: exclusive scan of the 196 block sums (single tiny block)
__global__ __launch_bounds__(256) void scan_partials(const int* __restrict__ bsum,
                                                     int* __restrict__ bscan, int* __restrict__ rowptr) {
  __shared__ int sh[256];
  int t = threadIdx.x;
  int v = (t < NB) ? bsum[t] : 0;
  sh[t] = v;
  __syncthreads();
  for (int off = 1; off < 256; off <<= 1) {
    int u = (t >= off) ? sh[t - off] : 0;
    __syncthreads();
    sh[t] += u;
    __syncthreads();
  }
  bscan[t] = sh[t] - v;           // exclusive
  if (t == 255) rowptr[NN] = sh[255];
}

// Phase C: intra-block exclusive scan + block offset -> rowptr
__global__ __launch_bounds__(256) void scan_final(const int* __restrict__ deg,
                                                  const int* __restrict__ bscan, int* __restrict__ rowptr) {
  __shared__ int sh[256];
  int t = threadIdx.x;
  int i = blockIdx.x * 256 + t;
  int v = (i < NN) ? deg[i] : 0;
  sh[t] = v;
  __syncthreads();
  for (int off = 1; off < 256; off <<= 1) {
    int u = (t >= off) ? sh[t - off] : 0;
    __syncthreads();
    sh[t] += u;
    __syncthreads();
  }
  if (i < NN) rowptr[i] = bscan[blockIdx.x] + sh[t] - v;
}

__global__ __launch_bounds__(256) void scatter(
    const int* __restrict__ src, const int* __restrict__ dst,
    const int* __restrict__ rowptr, int* __restrict__ cnt, int* __restrict__ csr_src) {
  int i = blockIdx.x * 256 + threadIdx.x;
  if (i >= NE) return;
  int d = dst[i];
  int pos = rowptr[d] + atomicAdd(&cnt[d], 1);
  csr_src[pos] = src[i];
}

// ---- Fused softmax + aggregation + bias + ReLU. One wave per node. ----
// Shift-invariant softmax: |e| <= ~4 here so exp(e) is safe without max-subtraction.
__global__ __launch_bounds__(256) void gat_agg(
    const int* __restrict__ rowptr, const int* __restrict__ csr_src,
    const float* __restrict__ el, const float* __restrict__ er,
    const float* __restrict__ z, const float* __restrict__ b,
    float* __restrict__ out) {
  int node = (int)((blockIdx.x * 256 + threadIdx.x) >> 6);
  int lane = threadIdx.x & 63;
  if (node >= NN) return;
  int beg = rowptr[node], end = rowptr[node + 1];
  float erd = er[node];

  float2 acc = make_float2(0.f, 0.f);
  float ssum = 0.f;
  for (int base = beg; base < end; base += 64) {
    int j = base + lane;
    int sn = 0; float w = 0.f;
    if (j < end) {
      sn = csr_src[j];
      float e = el[sn] + erd;
      e = (e > 0.f) ? e : NEG_SLOPE * e;
      w = __expf(e);
    }
    ssum += w;
    int cnt = min(64, end - base);
    int jj = 0;
    for (; jj + 4 <= cnt; jj += 4) {
      float w0 = __shfl(w, jj, 64),     w1 = __shfl(w, jj + 1, 64);
      float w2 = __shfl(w, jj + 2, 64), w3 = __shfl(w, jj + 3, 64);
      int   s0 = __shfl(sn, jj, 64),     s1 = __shfl(sn, jj + 1, 64);
      int   s2 = __shfl(sn, jj + 2, 64), s3 = __shfl(sn, jj + 3, 64);
      float2 z0 = *(const float2*)(z + (size_t)s0 * DD + lane * 2);
      float2 z1 = *(const float2*)(z + (size_t)s1 * DD + lane * 2);
      float2 z2 = *(const float2*)(z + (size_t)s2 * DD + lane * 2);
      float2 z3 = *(const float2*)(z + (size_t)s3 * DD + lane * 2);
      acc.x += w0 * z0.x; acc.y += w0 * z0.y;
      acc.x += w1 * z1.x; acc.y += w1 * z1.y;
      acc.x += w2 * z2.x; acc.y += w2 * z2.y;
      acc.x += w3 * z3.x; acc.y += w3 * z3.y;
    }
    for (; jj < cnt; jj++) {
      float wj = __shfl(w, jj, 64);
      int snj = __shfl(sn, jj, 64);
      float2 zv = *(const float2*)(z + (size_t)snj * DD + lane * 2);
      acc.x += wj * zv.x; acc.y += wj * zv.y;
    }
  }
#pragma unroll
  for (int off = 32; off; off >>= 1) ssum += __shfl_xor(ssum, off, 64);
  float inv_s = (end > beg) ? 1.f / ssum : 0.f;

  float2 bv = *(const float2*)(b + lane * 2);
  float ox = acc.x * inv_s + bv.x, oy = acc.y * inv_s + bv.y;
  *(float2*)(out + (size_t)node * DD + lane * 2) = make_float2(ox > 0.f ? ox : 0.f, oy > 0.f ? oy : 0.f);
}

extern "C" void kernel_launch(void* const* d_in, const int* in_sizes, int n_in,
                              void* d_out, int out_size, void* d_ws, size_t ws_size,
                              hipStream_t stream) {
  const float* f   = (const float*)d_in[0];
  const int*   src = (const int*)d_in[1];
  const int*   dst = (const int*)d_in[2];
  const float* W[3]  = {(const float*)d_in[3], (const float*)d_in[7],  (const float*)d_in[11]};
  const float* al[3] = {(const float*)d_in[4], (const float*)d_in[8],  (const float*)d_in[12]};
  const float* ar[3] = {(const float*)d_in[5], (const float*)d_in[9],  (const float*)d_in[13]};
  const float* bb[3] = {(const float*)d_in[6], (const float*)d_in[10], (const float*)d_in[14]};

  // ws layout: Wh[3] | Wl[3] (shorts) | z | h | el | er (floats) | ints
  short* Wh3 = (short*)d_ws;                 // 3 * 16384 shorts
  short* Wl3 = Wh3 + 3 * 16384;
  float* zbuf = (float*)(Wl3 + 3 * 16384);
  float* hbuf = zbuf + (size_t)NN * DD;
  float* el   = hbuf + (size_t)NN * DD;
  float* er   = el + NN;
  int* deg    = (int*)(er + NN);
  int* cnt    = deg + NN;
  int* rowptr = cnt + NN;
  int* bsum   = rowptr + (NN + 1);
  int* bscan  = bsum + 256;
  int* csr_src = bscan + 256;

  // CSR build + weight split (graph & weights fixed across the launch)
  hipMemsetAsync(deg, 0, NN * sizeof(int), stream);
  hipMemsetAsync(cnt, 0, NN * sizeof(int), stream);
  hist<<<(NE + 255) / 256, 256, 0, stream>>>(dst, deg);
  block_sums<<<NB, 256, 0, stream>>>(deg, bsum);
  scan_partials<<<1, 256, 0, stream>>>(bsum, bscan, rowptr);
  scan_final<<<NB, 256, 0, stream>>>(deg, bscan, rowptr);
  scatter<<<(NE + 255) / 256, 256, 0, stream>>>(src, dst, rowptr, cnt, csr_src);
  for (int L = 0; L < 3; L++)
    wsplit<<<16384 / 256, 256, 0, stream>>>(W[L], Wh3 + L * 16384, Wl3 + L * 16384);

  const float* x = f;
  for (int L = 0; L < 3; L++) {
    float* out = (L == 2) ? (float*)d_out : hbuf;
    gemm_mfma<<<(MWAVES + 3) / 4, 256, 0, stream>>>(x, Wh3 + L * 16384, Wl3 + L * 16384,
                                                    al[L], ar[L], zbuf, el, er);
    gat_agg<<<(NN * 64) / 256, 256, 0, stream>>>(rowptr, csr_src, el, er, zbuf, bb[L], out);
    x = out;
  }
}

// Round 5
// 408.622 us; speedup vs baseline: 6.0352x; 1.0134x over previous
//
#include <hip/hip_runtime.h>
#include <math.h>

#define NN 50000
#define NE 800000
#define DD 128
#define NEG_SLOPE 0.2f
#define NB ((NN + 255) / 256)     // 196 scan blocks
#define GWAVES ((NN + 31) / 32)   // 1563 gemm waves (32 rows each)

typedef short frag8 __attribute__((ext_vector_type(8)));
typedef float f32x4 __attribute__((ext_vector_type(4)));

// round-to-nearest-even fp32 -> bf16 (as ushort)
__device__ __forceinline__ unsigned bf16_rne(float x) {
  unsigned u = __float_as_uint(x);
  return (u + 0x7FFFu + ((u >> 16) & 1u)) >> 16;
}

// ---- W pre-split + pre-swizzle into MFMA B-fragment order, all 3 layers in one launch ----
// Wh[L*16384 + ((kt*8+nt)*64 + lane)*8 + j] = bf16_hi( W_L[kt*32 + (lane>>4)*8 + j][nt*16 + (lane&15)] )
__global__ __launch_bounds__(256) void wsplit3(
    const float* __restrict__ W0, const float* __restrict__ W1, const float* __restrict__ W2,
    short* __restrict__ Wh, short* __restrict__ Wl) {
  int gidx = blockIdx.x * 256 + threadIdx.x;          // 0..49151
  int L = gidx >> 14;
  int idx = gidx & 16383;
  const float* W = (L == 0) ? W0 : (L == 1) ? W1 : W2;
  int j = idx & 7;
  int lane = (idx >> 3) & 63;
  int tile = idx >> 9;                                // kt*8 + nt
  int nt = tile & 7, kt = tile >> 3;
  int k = kt * 32 + (lane >> 4) * 8 + j;
  int n = nt * 16 + (lane & 15);
  float x = W[k * DD + n];
  unsigned hu = bf16_rne(x);
  float hf = __uint_as_float(hu << 16);
  unsigned lu = bf16_rne(x - hf);
  Wh[gidx] = (short)hu;
  Wl[gidx] = (short)lu;
}

// ---- GEMM z = x@W via split-bf16 MFMA. 32 rows/wave (2 A-tiles share each B fragment). ----
// Fused el = z.al, er = z.ar.
__global__ __launch_bounds__(256) void gemm_mfma(
    const float* __restrict__ x, const short* __restrict__ Wh, const short* __restrict__ Wl,
    const float* __restrict__ al, const float* __restrict__ ar,
    float* __restrict__ z, float* __restrict__ el, float* __restrict__ er) {
  int wid = blockIdx.x * 4 + (threadIdx.x >> 6);
  if (wid >= GWAVES) return;
  int lane = threadIdx.x & 63;
  int m = lane & 15, quad = lane >> 4;
  int R0 = wid * 32;

  f32x4 acc0[8], acc1[8];
#pragma unroll
  for (int t = 0; t < 8; t++) { acc0[t] = (f32x4)(0.f); acc1[t] = (f32x4)(0.f); }

  // clamp OOB rows (garbage compute, stores guarded)
  int rA0 = R0 + m;        if (rA0 > NN - 1) rA0 = NN - 1;
  int rA1 = R0 + 16 + m;   if (rA1 > NN - 1) rA1 = NN - 1;

#pragma unroll
  for (int kt = 0; kt < 4; kt++) {
    const float* xp0 = x + (size_t)rA0 * DD + kt * 32 + quad * 8;
    const float* xp1 = x + (size_t)rA1 * DD + kt * 32 + quad * 8;
    float xv0[8], xv1[8];
    *(float4*)(xv0) = *(const float4*)xp0;
    *(float4*)(xv0 + 4) = *(const float4*)(xp0 + 4);
    *(float4*)(xv1) = *(const float4*)xp1;
    *(float4*)(xv1 + 4) = *(const float4*)(xp1 + 4);
    frag8 ah0, alo0, ah1, alo1;
#pragma unroll
    for (int j = 0; j < 8; j++) {
      unsigned hu = bf16_rne(xv0[j]);
      float hf = __uint_as_float(hu << 16);
      ah0[j] = (short)hu;
      alo0[j] = (short)bf16_rne(xv0[j] - hf);
      hu = bf16_rne(xv1[j]);
      hf = __uint_as_float(hu << 16);
      ah1[j] = (short)hu;
      alo1[j] = (short)bf16_rne(xv1[j] - hf);
    }
#pragma unroll
    for (int nt = 0; nt < 8; nt++) {
      int base = ((kt * 8 + nt) * 64 + lane) * 8;
      frag8 bh = *(const frag8*)(Wh + base);
      frag8 bl = *(const frag8*)(Wl + base);
      acc0[nt] = __builtin_amdgcn_mfma_f32_16x16x32_bf16(alo0, bh, acc0[nt], 0, 0, 0);
      acc0[nt] = __builtin_amdgcn_mfma_f32_16x16x32_bf16(ah0, bl, acc0[nt], 0, 0, 0);
      acc0[nt] = __builtin_amdgcn_mfma_f32_16x16x32_bf16(ah0, bh, acc0[nt], 0, 0, 0);
      acc1[nt] = __builtin_amdgcn_mfma_f32_16x16x32_bf16(alo1, bh, acc1[nt], 0, 0, 0);
      acc1[nt] = __builtin_amdgcn_mfma_f32_16x16x32_bf16(ah1, bl, acc1[nt], 0, 0, 0);
      acc1[nt] = __builtin_amdgcn_mfma_f32_16x16x32_bf16(ah1, bh, acc1[nt], 0, 0, 0);
    }
  }

  float alv[8], arv[8];
#pragma unroll
  for (int nt = 0; nt < 8; nt++) { alv[nt] = al[nt * 16 + m]; arv[nt] = ar[nt * 16 + m]; }

#pragma unroll
  for (int tile = 0; tile < 2; tile++) {
    f32x4* acc = tile ? acc1 : acc0;
    int rbase = R0 + tile * 16 + quad * 4;
#pragma unroll
    for (int r = 0; r < 4; r++) {
      float pl = 0.f, pr = 0.f;
#pragma unroll
      for (int nt = 0; nt < 8; nt++) { pl += acc[nt][r] * alv[nt]; pr += acc[nt][r] * arv[nt]; }
#pragma unroll
      for (int off = 8; off; off >>= 1) {
        pl += __shfl_xor(pl, off, 64);
        pr += __shfl_xor(pr, off, 64);
      }
      int row = rbase + r;
      if (row < NN) {
        if (m == 0) { el[row] = pl; er[row] = pr; }
#pragma unroll
        for (int nt = 0; nt < 8; nt++) z[(size_t)row * DD + nt * 16 + m] = acc[nt][r];
      }
    }
  }
}

// ---- CSR build (once per launch, reused by all 3 layers) ----
__global__ __launch_bounds__(256) void hist(const int* __restrict__ dst, int* __restrict__ deg) {
  int i = blockIdx.x * 256 + threadIdx.x;
  if (i < NE) atomicAdd(&deg[dst[i]], 1);
}

__global__ __launch_bounds__(256) void block_sums(const int* __restrict__ deg, int* __restrict__ bsum) {
  int i = blockIdx.x * 256 + threadIdx.x;
  int v = (i < NN) ? deg[i] : 0;
#pragma unroll
  for (int off = 32; off; off >>= 1) v += __shfl_xor(v, off, 64);
  __shared__ int wsum[4];
  if ((threadIdx.x & 63) == 0) wsum[threadIdx.x >> 6] = v;
  __syncthreads();
  if (threadIdx.x == 0) bsum[blockIdx.x] = wsum[0] + wsum[1] + wsum[2] + wsum[3];
}

__global__ __launch_bounds__(256) void scan_partials(const int* __restrict__ bsum,
                                                     int* __restrict__ bscan, int* __restrict__ rowptr) {
  __shared__ int sh[256];
  int t = threadIdx.x;
  int v = (t < NB) ? bsum[t] : 0;
  sh[t] = v;
  __syncthreads();
  for (int off = 1; off < 256; off <<= 1) {
    int u = (t >= off) ? sh[t - off] : 0;
    __syncthreads();
    sh[t] += u;
    __syncthreads();
  }
  bscan[t] = sh[t] - v;
  if (t == 255) rowptr[NN] = sh[255];
}

__global__ __launch_bounds__(256) void scan_final(const int* __restrict__ deg,
                                                  const int* __restrict__ bscan, int* __restrict__ rowptr) {
  __shared__ int sh[256];
  int t = threadIdx.x;
  int i = blockIdx.x * 256 + t;
  int v = (i < NN) ? deg[i] : 0;
  sh[t] = v;
  __syncthreads();
  for (int off = 1; off < 256; off <<= 1) {
    int u = (t >= off) ? sh[t - off] : 0;
    __syncthreads();
    sh[t] += u;
    __syncthreads();
  }
  if (i < NN) rowptr[i] = bscan[blockIdx.x] + sh[t] - v;
}

__global__ __launch_bounds__(256) void scatter(
    const int* __restrict__ src, const int* __restrict__ dst,
    const int* __restrict__ rowptr, int* __restrict__ cnt, int* __restrict__ csr_src) {
  int i = blockIdx.x * 256 + threadIdx.x;
  if (i >= NE) return;
  int d = dst[i];
  int pos = rowptr[d] + atomicAdd(&cnt[d], 1);
  csr_src[pos] = src[i];
}

// ---- Fused softmax + aggregation + bias + ReLU. One wave per node, unroll 8. ----
__global__ __launch_bounds__(256) void gat_agg(
    const int* __restrict__ rowptr, const int* __restrict__ csr_src,
    const float* __restrict__ el, const float* __restrict__ er,
    const float* __restrict__ z, const float* __restrict__ b,
    float* __restrict__ out) {
  int node = (int)((blockIdx.x * 256 + threadIdx.x) >> 6);
  int lane = threadIdx.x & 63;
  if (node >= NN) return;
  int beg = rowptr[node], end = rowptr[node + 1];
  float erd = er[node];
  const float* zb = z + lane * 2;

  float2 acc = make_float2(0.f, 0.f);
  float ssum = 0.f;
  for (int base = beg; base < end; base += 64) {
    int j = base + lane;
    int sn = 0; float w = 0.f;
    if (j < end) {
      sn = csr_src[j];
      float e = el[sn] + erd;
      e = (e > 0.f) ? e : NEG_SLOPE * e;
      w = __expf(e);
    }
    ssum += w;
    int cnt = min(64, end - base);
    int jj = 0;
    for (; jj + 8 <= cnt; jj += 8) {
      float ww[8]; int ss[8];
#pragma unroll
      for (int u = 0; u < 8; u++) {
        ww[u] = __shfl(w, jj + u, 64);
        ss[u] = __shfl(sn, jj + u, 64);
      }
      float2 zv[8];
#pragma unroll
      for (int u = 0; u < 8; u++) zv[u] = *(const float2*)(zb + (size_t)ss[u] * DD);
#pragma unroll
      for (int u = 0; u < 8; u++) { acc.x += ww[u] * zv[u].x; acc.y += ww[u] * zv[u].y; }
    }
    for (; jj < cnt; jj++) {
      float wj = __shfl(w, jj, 64);
      int snj = __shfl(sn, jj, 64);
      float2 zv = *(const float2*)(zb + (size_t)snj * DD);
      acc.x += wj * zv.x; acc.y += wj * zv.y;
    }
  }
#pragma unroll
  for (int off = 32; off; off >>= 1) ssum += __shfl_xor(ssum, off, 64);
  float inv_s = (end > beg) ? 1.f / ssum : 0.f;

  float2 bv = *(const float2*)(b + lane * 2);
  float ox = acc.x * inv_s + bv.x, oy = acc.y * inv_s + bv.y;
  *(float2*)(out + (size_t)node * DD + lane * 2) = make_float2(ox > 0.f ? ox : 0.f, oy > 0.f ? oy : 0.f);
}

extern "C" void kernel_launch(void* const* d_in, const int* in_sizes, int n_in,
                              void* d_out, int out_size, void* d_ws, size_t ws_size,
                              hipStream_t stream) {
  const float* f   = (const float*)d_in[0];
  const int*   src = (const int*)d_in[1];
  const int*   dst = (const int*)d_in[2];
  const float* W[3]  = {(const float*)d_in[3], (const float*)d_in[7],  (const float*)d_in[11]};
  const float* al[3] = {(const float*)d_in[4], (const float*)d_in[8],  (const float*)d_in[12]};
  const float* ar[3] = {(const float*)d_in[5], (const float*)d_in[9],  (const float*)d_in[13]};
  const float* bb[3] = {(const float*)d_in[6], (const float*)d_in[10], (const float*)d_in[14]};

  // ws layout: Wh[3] | Wl[3] (shorts) | z | h | el | er (floats) | deg | cnt | rowptr | bsum | bscan | csr_src
  short* Wh3 = (short*)d_ws;                 // 3 * 16384 shorts
  short* Wl3 = Wh3 + 3 * 16384;
  float* zbuf = (float*)(Wl3 + 3 * 16384);
  float* hbuf = zbuf + (size_t)NN * DD;
  float* el   = hbuf + (size_t)NN * DD;
  float* er   = el + NN;
  int* deg    = (int*)(er + NN);
  int* cnt    = deg + NN;
  int* rowptr = cnt + NN;
  int* bsum   = rowptr + (NN + 1);
  int* bscan  = bsum + 256;
  int* csr_src = bscan + 256;

  // CSR build + weight split (graph & weights fixed across the launch)
  hipMemsetAsync(deg, 0, 2 * NN * sizeof(int), stream);   // deg + cnt (adjacent)
  hist<<<(NE + 255) / 256, 256, 0, stream>>>(dst, deg);
  block_sums<<<NB, 256, 0, stream>>>(deg, bsum);
  scan_partials<<<1, 256, 0, stream>>>(bsum, bscan, rowptr);
  scan_final<<<NB, 256, 0, stream>>>(deg, bscan, rowptr);
  scatter<<<(NE + 255) / 256, 256, 0, stream>>>(src, dst, rowptr, cnt, csr_src);
  wsplit3<<<3 * 16384 / 256, 256, 0, stream>>>(W[0], W[1], W[2], Wh3, Wl3);

  const float* x = f;
  for (int L = 0; L < 3; L++) {
    float* out = (L == 2) ? (float*)d_out : hbuf;
    gemm_mfma<<<(GWAVES + 3) / 4, 256, 0, stream>>>(x, Wh3 + L * 16384, Wl3 + L * 16384,
                                                    al[L], ar[L], zbuf, el, er);
    gat_agg<<<(NN * 64) / 256, 256, 0, stream>>>(rowptr, csr_src, el, er, zbuf, bb[L], out);
    x = out;
  }
}

// Round 6
// 397.780 us; speedup vs baseline: 6.1997x; 1.0273x over previous
//
#include <hip/hip_runtime.h>
#include <math.h>

#define NN 50000
#define NE 800000
#define DD 128
#define NEG_SLOPE 0.2f
#define NB ((NN + 255) / 256)     // 196 scan blocks
#define GBLK ((NN + 63) / 64)     // 782 gemm blocks (64 rows/block, 16/wave)

typedef short frag8 __attribute__((ext_vector_type(8)));
typedef float f32x4 __attribute__((ext_vector_type(4)));

// round-to-nearest-even fp32 -> bf16 (as ushort)
__device__ __forceinline__ unsigned bf16_rne(float x) {
  unsigned u = __float_as_uint(x);
  return (u + 0x7FFFu + ((u >> 16) & 1u)) >> 16;
}

// ---- W pre-split + pre-swizzle into MFMA B-fragment order, all 3 layers in one launch ----
// Wh[L*16384 + kt*4096 + nt*512 + lane*8 + j] = bf16_hi( W_L[kt*32 + (lane>>4)*8 + j][nt*16 + (lane&15)] )
__global__ __launch_bounds__(256) void wsplit3(
    const float* __restrict__ W0, const float* __restrict__ W1, const float* __restrict__ W2,
    short* __restrict__ Wh, short* __restrict__ Wl) {
  int gidx = blockIdx.x * 256 + threadIdx.x;          // 0..49151
  int L = gidx >> 14;
  int idx = gidx & 16383;
  const float* W = (L == 0) ? W0 : (L == 1) ? W1 : W2;
  int j = idx & 7;
  int lane = (idx >> 3) & 63;
  int tile = idx >> 9;                                // kt*8 + nt
  int nt = tile & 7, kt = tile >> 3;
  int k = kt * 32 + (lane >> 4) * 8 + j;
  int n = nt * 16 + (lane & 15);
  float x = W[k * DD + n];
  unsigned hu = bf16_rne(x);
  float hf = __uint_as_float(hu << 16);
  unsigned lu = bf16_rne(x - hf);
  Wh[gidx] = (short)hu;
  Wl[gidx] = (short)lu;
}

// ---- GEMM z = x@W via split-bf16 MFMA. 4-wave block shares B via double-buffered LDS. ----
// Wave handles 16 rows; block = 64 rows. Fused el = z.al, er = z.ar.
__global__ __launch_bounds__(256) void gemm_mfma(
    const float* __restrict__ x, const short* __restrict__ Wh, const short* __restrict__ Wl,
    const float* __restrict__ al, const float* __restrict__ ar,
    float* __restrict__ z, float* __restrict__ el, float* __restrict__ er) {
  __shared__ __align__(16) short sB[2][8192];  // [buf][h*4096 + nt*512 + lane*8 + j]
  const int t = threadIdx.x;
  const int w = t >> 6, lane = t & 63;
  const int m = lane & 15, quad = lane >> 4;
  const int R0 = blockIdx.x * 64 + w * 16;

  // flat 16 KB stage of one kt-slab (Wh 8 KB | Wl 8 KB), layouts match fragment order
  auto stage = [&](int kt, int buf) {
    const uint4* gh = (const uint4*)(Wh + kt * 4096);   // 512 uint4
    const uint4* gl = (const uint4*)(Wl + kt * 4096);
    uint4* s = (uint4*)sB[buf];                         // 1024 uint4
    s[t] = gh[t];
    s[t + 256] = gh[t + 256];
    s[t + 512] = gl[t];
    s[t + 768] = gl[t + 256];
  };

  f32x4 acc[8];
#pragma unroll
  for (int nt = 0; nt < 8; nt++) acc[nt] = (f32x4)(0.f);

  int rA = R0 + m; if (rA > NN - 1) rA = NN - 1;  // clamp OOB rows; stores guarded

  stage(0, 0);
  __syncthreads();

#pragma unroll
  for (int kt = 0; kt < 4; kt++) {
    const int buf = kt & 1;
    if (kt < 3) stage(kt + 1, buf ^ 1);

    const float* xp = x + (size_t)rA * DD + kt * 32 + quad * 8;
    float xv[8];
    *(float4*)(xv) = *(const float4*)xp;
    *(float4*)(xv + 4) = *(const float4*)(xp + 4);
    frag8 ah, alo;
#pragma unroll
    for (int j = 0; j < 8; j++) {
      unsigned hu = bf16_rne(xv[j]);
      float hf = __uint_as_float(hu << 16);
      ah[j] = (short)hu;
      alo[j] = (short)bf16_rne(xv[j] - hf);
    }
#pragma unroll
    for (int nt = 0; nt < 8; nt++) {
      frag8 bh = *(const frag8*)&sB[buf][nt * 512 + lane * 8];
      frag8 bl = *(const frag8*)&sB[buf][4096 + nt * 512 + lane * 8];
      acc[nt] = __builtin_amdgcn_mfma_f32_16x16x32_bf16(alo, bh, acc[nt], 0, 0, 0);
      acc[nt] = __builtin_amdgcn_mfma_f32_16x16x32_bf16(ah, bl, acc[nt], 0, 0, 0);
      acc[nt] = __builtin_amdgcn_mfma_f32_16x16x32_bf16(ah, bh, acc[nt], 0, 0, 0);
    }
    __syncthreads();
  }

  float alv[8], arv[8];
#pragma unroll
  for (int nt = 0; nt < 8; nt++) { alv[nt] = al[nt * 16 + m]; arv[nt] = ar[nt * 16 + m]; }
#pragma unroll
  for (int r = 0; r < 4; r++) {
    float pl = 0.f, pr = 0.f;
#pragma unroll
    for (int nt = 0; nt < 8; nt++) { pl += acc[nt][r] * alv[nt]; pr += acc[nt][r] * arv[nt]; }
#pragma unroll
    for (int off = 8; off; off >>= 1) {
      pl += __shfl_xor(pl, off, 64);
      pr += __shfl_xor(pr, off, 64);
    }
    int row = R0 + quad * 4 + r;
    if (row < NN) {
      if (m == 0) { el[row] = pl; er[row] = pr; }
#pragma unroll
      for (int nt = 0; nt < 8; nt++) z[(size_t)row * DD + nt * 16 + m] = acc[nt][r];
    }
  }
}

// ---- CSR build (once per launch, reused by all 3 layers) ----
__global__ __launch_bounds__(256) void hist(const int* __restrict__ dst, int* __restrict__ deg) {
  int i = blockIdx.x * 256 + threadIdx.x;
  if (i < NE) atomicAdd(&deg[dst[i]], 1);
}

__global__ __launch_bounds__(256) void block_sums(const int* __restrict__ deg, int* __restrict__ bsum) {
  int i = blockIdx.x * 256 + threadIdx.x;
  int v = (i < NN) ? deg[i] : 0;
#pragma unroll
  for (int off = 32; off; off >>= 1) v += __shfl_xor(v, off, 64);
  __shared__ int wsum[4];
  if ((threadIdx.x & 63) == 0) wsum[threadIdx.x >> 6] = v;
  __syncthreads();
  if (threadIdx.x == 0) bsum[blockIdx.x] = wsum[0] + wsum[1] + wsum[2] + wsum[3];
}

__global__ __launch_bounds__(256) void scan_partials(const int* __restrict__ bsum,
                                                     int* __restrict__ bscan, int* __restrict__ rowptr) {
  __shared__ int sh[256];
  int t = threadIdx.x;
  int v = (t < NB) ? bsum[t] : 0;
  sh[t] = v;
  __syncthreads();
  for (int off = 1; off < 256; off <<= 1) {
    int u = (t >= off) ? sh[t - off] : 0;
    __syncthreads();
    sh[t] += u;
    __syncthreads();
  }
  bscan[t] = sh[t] - v;
  if (t == 255) rowptr[NN] = sh[255];
}

__global__ __launch_bounds__(256) void scan_final(const int* __restrict__ deg,
                                                  const int* __restrict__ bscan, int* __restrict__ rowptr) {
  __shared__ int sh[256];
  int t = threadIdx.x;
  int i = blockIdx.x * 256 + t;
  int v = (i < NN) ? deg[i] : 0;
  sh[t] = v;
  __syncthreads();
  for (int off = 1; off < 256; off <<= 1) {
    int u = (t >= off) ? sh[t - off] : 0;
    __syncthreads();
    sh[t] += u;
    __syncthreads();
  }
  if (i < NN) rowptr[i] = bscan[blockIdx.x] + sh[t] - v;
}

__global__ __launch_bounds__(256) void scatter(
    const int* __restrict__ src, const int* __restrict__ dst,
    const int* __restrict__ rowptr, int* __restrict__ cnt, int* __restrict__ csr_src) {
  int i = blockIdx.x * 256 + threadIdx.x;
  if (i >= NE) return;
  int d = dst[i];
  int pos = rowptr[d] + atomicAdd(&cnt[d], 1);
  csr_src[pos] = src[i];
}

// ---- Fused softmax + aggregation + bias + ReLU. One wave per node, unroll 8. ----
__global__ __launch_bounds__(256) void gat_agg(
    const int* __restrict__ rowptr, const int* __restrict__ csr_src,
    const float* __restrict__ el, const float* __restrict__ er,
    const float* __restrict__ z, const float* __restrict__ b,
    float* __restrict__ out) {
  int node = (int)((blockIdx.x * 256 + threadIdx.x) >> 6);
  int lane = threadIdx.x & 63;
  if (node >= NN) return;
  int beg = rowptr[node], end = rowptr[node + 1];
  float erd = er[node];
  const float* zb = z + lane * 2;

  float2 acc = make_float2(0.f, 0.f);
  float ssum = 0.f;
  for (int base = beg; base < end; base += 64) {
    int j = base + lane;
    int sn = 0; float w = 0.f;
    if (j < end) {
      sn = csr_src[j];
      float e = el[sn] + erd;
      e = (e > 0.f) ? e : NEG_SLOPE * e;
      w = __expf(e);
    }
    ssum += w;
    int cnt = min(64, end - base);
    int jj = 0;
    for (; jj + 8 <= cnt; jj += 8) {
      float ww[8]; int ss[8];
#pragma unroll
      for (int u = 0; u < 8; u++) {
        ww[u] = __shfl(w, jj + u, 64);
        ss[u] = __shfl(sn, jj + u, 64);
      }
      float2 zv[8];
#pragma unroll
      for (int u = 0; u < 8; u++) zv[u] = *(const float2*)(zb + (size_t)ss[u] * DD);
#pragma unroll
      for (int u = 0; u < 8; u++) { acc.x += ww[u] * zv[u].x; acc.y += ww[u] * zv[u].y; }
    }
    for (; jj < cnt; jj++) {
      float wj = __shfl(w, jj, 64);
      int snj = __shfl(sn, jj, 64);
      float2 zv = *(const float2*)(zb + (size_t)snj * DD);
      acc.x += wj * zv.x; acc.y += wj * zv.y;
    }
  }
#pragma unroll
  for (int off = 32; off; off >>= 1) ssum += __shfl_xor(ssum, off, 64);
  float inv_s = (end > beg) ? 1.f / ssum : 0.f;

  float2 bv = *(const float2*)(b + lane * 2);
  float ox = acc.x * inv_s + bv.x, oy = acc.y * inv_s + bv.y;
  *(float2*)(out + (size_t)node * DD + lane * 2) = make_float2(ox > 0.f ? ox : 0.f, oy > 0.f ? oy : 0.f);
}

extern "C" void kernel_launch(void* const* d_in, const int* in_sizes, int n_in,
                              void* d_out, int out_size, void* d_ws, size_t ws_size,
                              hipStream_t stream) {
  const float* f   = (const float*)d_in[0];
  const int*   src = (const int*)d_in[1];
  const int*   dst = (const int*)d_in[2];
  const float* W[3]  = {(const float*)d_in[3], (const float*)d_in[7],  (const float*)d_in[11]};
  const float* al[3] = {(const float*)d_in[4], (const float*)d_in[8],  (const float*)d_in[12]};
  const float* ar[3] = {(const float*)d_in[5], (const float*)d_in[9],  (const float*)d_in[13]};
  const float* bb[3] = {(const float*)d_in[6], (const float*)d_in[10], (const float*)d_in[14]};

  // ws layout: Wh[3] | Wl[3] (shorts) | z | h | el | er (floats) | deg | cnt | rowptr | bsum | bscan | csr_src
  short* Wh3 = (short*)d_ws;                 // 3 * 16384 shorts
  short* Wl3 = Wh3 + 3 * 16384;
  float* zbuf = (float*)(Wl3 + 3 * 16384);
  float* hbuf = zbuf + (size_t)NN * DD;
  float* el   = hbuf + (size_t)NN * DD;
  float* er   = el + NN;
  int* deg    = (int*)(er + NN);
  int* cnt    = deg + NN;
  int* rowptr = cnt + NN;
  int* bsum   = rowptr + (NN + 1);
  int* bscan  = bsum + 256;
  int* csr_src = bscan + 256;

  // CSR build + weight split (graph & weights fixed across the launch)
  hipMemsetAsync(deg, 0, 2 * NN * sizeof(int), stream);   // deg + cnt (adjacent)
  hist<<<(NE + 255) / 256, 256, 0, stream>>>(dst, deg);
  block_sums<<<NB, 256, 0, stream>>>(deg, bsum);
  scan_partials<<<1, 256, 0, stream>>>(bsum, bscan, rowptr);
  scan_final<<<NB, 256, 0, stream>>>(deg, bscan, rowptr);
  scatter<<<(NE + 255) / 256, 256, 0, stream>>>(src, dst, rowptr, cnt, csr_src);
  wsplit3<<<3 * 16384 / 256, 256, 0, stream>>>(W[0], W[1], W[2], Wh3, Wl3);

  const float* x = f;
  for (int L = 0; L < 3; L++) {
    float* out = (L == 2) ? (float*)d_out : hbuf;
    gemm_mfma<<<GBLK, 256, 0, stream>>>(x, Wh3 + L * 16384, Wl3 + L * 16384,
                                        al[L], ar[L], zbuf, el, er);
    gat_agg<<<(NN * 64) / 256, 256, 0, stream>>>(rowptr, csr_src, el, er, zbuf, bb[L], out);
    x = out;
  }
}

// Round 7
// 379.481 us; speedup vs baseline: 6.4986x; 1.0482x over previous
//
#include <hip/hip_runtime.h>
#include <math.h>

#define NN 50000
#define NE 800000
#define DD 128
#define NEG_SLOPE 0.2f
#define NB ((NN + 255) / 256)     // 196 scan blocks
#define GBLK ((NN + 63) / 64)     // 782 gemm blocks (64 rows/block, 16/wave)
#define WSBLK (3 * 16384 / 256)   // 192 wsplit blocks
#define HBLK ((NE + 255) / 256)   // 3125 hist/scatter blocks

typedef short frag8 __attribute__((ext_vector_type(8)));
typedef float f32x4 __attribute__((ext_vector_type(4)));

// round-to-nearest-even fp32 -> bf16 (as ushort)
__device__ __forceinline__ unsigned bf16_rne(float x) {
  unsigned u = __float_as_uint(x);
  return (u + 0x7FFFu + ((u >> 16) & 1u)) >> 16;
}

// ---- wsplit body: W pre-split + pre-swizzle into MFMA B-fragment order ----
__device__ __forceinline__ void wsplit_body(
    int bid, const float* __restrict__ W0, const float* __restrict__ W1,
    const float* __restrict__ W2, short* __restrict__ Wh, short* __restrict__ Wl) {
  int gidx = bid * 256 + threadIdx.x;                 // 0..49151
  int L = gidx >> 14;
  int idx = gidx & 16383;
  const float* W = (L == 0) ? W0 : (L == 1) ? W1 : W2;
  int j = idx & 7;
  int lane = (idx >> 3) & 63;
  int tile = idx >> 9;                                // kt*8 + nt
  int nt = tile & 7, kt = tile >> 3;
  int k = kt * 32 + (lane >> 4) * 8 + j;
  int n = nt * 16 + (lane & 15);
  float x = W[k * DD + n];
  unsigned hu = bf16_rne(x);
  float hf = __uint_as_float(hu << 16);
  unsigned lu = bf16_rne(x - hf);
  Wh[gidx] = (short)hu;
  Wl[gidx] = (short)lu;
}

__device__ __forceinline__ void hist_body(int bid, const int* __restrict__ dst,
                                          int* __restrict__ deg) {
  int i = bid * 256 + threadIdx.x;
  if (i < NE) atomicAdd(&deg[dst[i]], 1);
}

// fused: wsplit (192 blocks) || hist (3125 blocks) — both depend only on inputs
__global__ __launch_bounds__(256) void fused_pre(
    const float* __restrict__ W0, const float* __restrict__ W1, const float* __restrict__ W2,
    short* __restrict__ Wh, short* __restrict__ Wl,
    const int* __restrict__ dst, int* __restrict__ deg) {
  if (blockIdx.x < WSBLK) wsplit_body(blockIdx.x, W0, W1, W2, Wh, Wl);
  else hist_body(blockIdx.x - WSBLK, dst, deg);
}

// ---- GEMM body: z = x@W via split-bf16 MFMA, 4-wave block shares B via dbuf LDS ----
__device__ __forceinline__ void gemm_body(
    int bid, short (*sB)[8192],
    const float* __restrict__ x, const short* __restrict__ Wh, const short* __restrict__ Wl,
    const float* __restrict__ al, const float* __restrict__ ar,
    float* __restrict__ z, float* __restrict__ el, float* __restrict__ er) {
  const int t = threadIdx.x;
  const int w = t >> 6, lane = t & 63;
  const int m = lane & 15, quad = lane >> 4;
  const int R0 = bid * 64 + w * 16;

  auto stage = [&](int kt, int buf) {
    const uint4* gh = (const uint4*)(Wh + kt * 4096);
    const uint4* gl = (const uint4*)(Wl + kt * 4096);
    uint4* s = (uint4*)sB[buf];
    s[t] = gh[t];
    s[t + 256] = gh[t + 256];
    s[t + 512] = gl[t];
    s[t + 768] = gl[t + 256];
  };

  f32x4 acc[8];
#pragma unroll
  for (int nt = 0; nt < 8; nt++) acc[nt] = (f32x4)(0.f);

  int rA = R0 + m; if (rA > NN - 1) rA = NN - 1;  // clamp OOB rows; stores guarded

  stage(0, 0);
  __syncthreads();

#pragma unroll
  for (int kt = 0; kt < 4; kt++) {
    const int buf = kt & 1;
    if (kt < 3) stage(kt + 1, buf ^ 1);

    const float* xp = x + (size_t)rA * DD + kt * 32 + quad * 8;
    float xv[8];
    *(float4*)(xv) = *(const float4*)xp;
    *(float4*)(xv + 4) = *(const float4*)(xp + 4);
    frag8 ah, alo;
#pragma unroll
    for (int j = 0; j < 8; j++) {
      unsigned hu = bf16_rne(xv[j]);
      float hf = __uint_as_float(hu << 16);
      ah[j] = (short)hu;
      alo[j] = (short)bf16_rne(xv[j] - hf);
    }
#pragma unroll
    for (int nt = 0; nt < 8; nt++) {
      frag8 bh = *(const frag8*)&sB[buf][nt * 512 + lane * 8];
      frag8 bl = *(const frag8*)&sB[buf][4096 + nt * 512 + lane * 8];
      acc[nt] = __builtin_amdgcn_mfma_f32_16x16x32_bf16(alo, bh, acc[nt], 0, 0, 0);
      acc[nt] = __builtin_amdgcn_mfma_f32_16x16x32_bf16(ah, bl, acc[nt], 0, 0, 0);
      acc[nt] = __builtin_amdgcn_mfma_f32_16x16x32_bf16(ah, bh, acc[nt], 0, 0, 0);
    }
    __syncthreads();
  }

  float alv[8], arv[8];
#pragma unroll
  for (int nt = 0; nt < 8; nt++) { alv[nt] = al[nt * 16 + m]; arv[nt] = ar[nt * 16 + m]; }
#pragma unroll
  for (int r = 0; r < 4; r++) {
    float pl = 0.f, pr = 0.f;
#pragma unroll
    for (int nt = 0; nt < 8; nt++) { pl += acc[nt][r] * alv[nt]; pr += acc[nt][r] * arv[nt]; }
#pragma unroll
    for (int off = 8; off; off >>= 1) {
      pl += __shfl_xor(pl, off, 64);
      pr += __shfl_xor(pr, off, 64);
    }
    int row = R0 + quad * 4 + r;
    if (row < NN) {
      if (m == 0) { el[row] = pl; er[row] = pr; }
#pragma unroll
      for (int nt = 0; nt < 8; nt++) z[(size_t)row * DD + nt * 16 + m] = acc[nt][r];
    }
  }
}

__device__ __forceinline__ void scatter_body(
    int bid, const int* __restrict__ src, const int* __restrict__ dst,
    const int* __restrict__ rowptr, int* __restrict__ cnt, int* __restrict__ csr_src) {
  int i = bid * 256 + threadIdx.x;
  if (i >= NE) return;
  int d = dst[i];
  int pos = rowptr[d] + atomicAdd(&cnt[d], 1);
  csr_src[pos] = src[i];
}

// standalone gemm for layers 1,2
__global__ __launch_bounds__(256) void gemm_mfma(
    const float* __restrict__ x, const short* __restrict__ Wh, const short* __restrict__ Wl,
    const float* __restrict__ al, const float* __restrict__ ar,
    float* __restrict__ z, float* __restrict__ el, float* __restrict__ er) {
  __shared__ __align__(16) short sB[2][8192];
  gemm_body(blockIdx.x, sB, x, Wh, Wl, al, ar, z, el, er);
}

// fused: gemm0 (782 blocks, scheduled first) || scatter (3125 blocks)
__global__ __launch_bounds__(256) void fused_scatter_gemm(
    const float* __restrict__ x, const short* __restrict__ Wh, const short* __restrict__ Wl,
    const float* __restrict__ al, const float* __restrict__ ar,
    float* __restrict__ z, float* __restrict__ el, float* __restrict__ er,
    const int* __restrict__ src, const int* __restrict__ dst,
    const int* __restrict__ rowptr, int* __restrict__ cnt, int* __restrict__ csr_src) {
  __shared__ __align__(16) short sB[2][8192];
  if (blockIdx.x < GBLK) gemm_body(blockIdx.x, sB, x, Wh, Wl, al, ar, z, el, er);
  else scatter_body(blockIdx.x - GBLK, src, dst, rowptr, cnt, csr_src);
}

// ---- scan kernels ----
__global__ __launch_bounds__(256) void block_sums(const int* __restrict__ deg, int* __restrict__ bsum) {
  int i = blockIdx.x * 256 + threadIdx.x;
  int v = (i < NN) ? deg[i] : 0;
#pragma unroll
  for (int off = 32; off; off >>= 1) v += __shfl_xor(v, off, 64);
  __shared__ int wsum[4];
  if ((threadIdx.x & 63) == 0) wsum[threadIdx.x >> 6] = v;
  __syncthreads();
  if (threadIdx.x == 0) bsum[blockIdx.x] = wsum[0] + wsum[1] + wsum[2] + wsum[3];
}

__global__ __launch_bounds__(256) void scan_partials(const int* __restrict__ bsum,
                                                     int* __restrict__ bscan, int* __restrict__ rowptr) {
  __shared__ int sh[256];
  int t = threadIdx.x;
  int v = (t < NB) ? bsum[t] : 0;
  sh[t] = v;
  __syncthreads();
  for (int off = 1; off < 256; off <<= 1) {
    int u = (t >= off) ? sh[t - off] : 0;
    __syncthreads();
    sh[t] += u;
    __syncthreads();
  }
  bscan[t] = sh[t] - v;
  if (t == 255) rowptr[NN] = sh[255];
}

__global__ __launch_bounds__(256) void scan_final(const int* __restrict__ deg,
                                                  const int* __restrict__ bscan, int* __restrict__ rowptr) {
  __shared__ int sh[256];
  int t = threadIdx.x;
  int i = blockIdx.x * 256 + t;
  int v = (i < NN) ? deg[i] : 0;
  sh[t] = v;
  __syncthreads();
  for (int off = 1; off < 256; off <<= 1) {
    int u = (t >= off) ? sh[t - off] : 0;
    __syncthreads();
    sh[t] += u;
    __syncthreads();
  }
  if (i < NN) rowptr[i] = bscan[blockIdx.x] + sh[t] - v;
}

// ---- Fused softmax + aggregation + bias + ReLU. One wave per node, unroll 8. ----
__global__ __launch_bounds__(256) void gat_agg(
    const int* __restrict__ rowptr, const int* __restrict__ csr_src,
    const float* __restrict__ el, const float* __restrict__ er,
    const float* __restrict__ z, const float* __restrict__ b,
    float* __restrict__ out) {
  int node = (int)((blockIdx.x * 256 + threadIdx.x) >> 6);
  int lane = threadIdx.x & 63;
  if (node >= NN) return;
  int beg = rowptr[node], end = rowptr[node + 1];
  float erd = er[node];
  const float* zb = z + lane * 2;

  float2 acc = make_float2(0.f, 0.f);
  float ssum = 0.f;
  for (int base = beg; base < end; base += 64) {
    int j = base + lane;
    int sn = 0; float w = 0.f;
    if (j < end) {
      sn = csr_src[j];
      float e = el[sn] + erd;
      e = (e > 0.f) ? e : NEG_SLOPE * e;
      w = __expf(e);
    }
    ssum += w;
    int cnt = min(64, end - base);
    int jj = 0;
    for (; jj + 8 <= cnt; jj += 8) {
      float ww[8]; int ss[8];
#pragma unroll
      for (int u = 0; u < 8; u++) {
        ww[u] = __shfl(w, jj + u, 64);
        ss[u] = __shfl(sn, jj + u, 64);
      }
      float2 zv[8];
#pragma unroll
      for (int u = 0; u < 8; u++) zv[u] = *(const float2*)(zb + (size_t)ss[u] * DD);
#pragma unroll
      for (int u = 0; u < 8; u++) { acc.x += ww[u] * zv[u].x; acc.y += ww[u] * zv[u].y; }
    }
    for (; jj < cnt; jj++) {
      float wj = __shfl(w, jj, 64);
      int snj = __shfl(sn, jj, 64);
      float2 zv = *(const float2*)(zb + (size_t)snj * DD);
      acc.x += wj * zv.x; acc.y += wj * zv.y;
    }
  }
#pragma unroll
  for (int off = 32; off; off >>= 1) ssum += __shfl_xor(ssum, off, 64);
  float inv_s = (end > beg) ? 1.f / ssum : 0.f;

  float2 bv = *(const float2*)(b + lane * 2);
  float ox = acc.x * inv_s + bv.x, oy = acc.y * inv_s + bv.y;
  *(float2*)(out + (size_t)node * DD + lane * 2) = make_float2(ox > 0.f ? ox : 0.f, oy > 0.f ? oy : 0.f);
}

extern "C" void kernel_launch(void* const* d_in, const int* in_sizes, int n_in,
                              void* d_out, int out_size, void* d_ws, size_t ws_size,
                              hipStream_t stream) {
  const float* f   = (const float*)d_in[0];
  const int*   src = (const int*)d_in[1];
  const int*   dst = (const int*)d_in[2];
  const float* W[3]  = {(const float*)d_in[3], (const float*)d_in[7],  (const float*)d_in[11]};
  const float* al[3] = {(const float*)d_in[4], (const float*)d_in[8],  (const float*)d_in[12]};
  const float* ar[3] = {(const float*)d_in[5], (const float*)d_in[9],  (const float*)d_in[13]};
  const float* bb[3] = {(const float*)d_in[6], (const float*)d_in[10], (const float*)d_in[14]};

  // ws layout: Wh[3] | Wl[3] (shorts) | z | h | el | er (floats) | deg | cnt | rowptr | bsum | bscan | csr_src
  short* Wh3 = (short*)d_ws;                 // 3 * 16384 shorts
  short* Wl3 = Wh3 + 3 * 16384;
  float* zbuf = (float*)(Wl3 + 3 * 16384);
  float* hbuf = zbuf + (size_t)NN * DD;
  float* el   = hbuf + (size_t)NN * DD;
  float* er   = el + NN;
  int* deg    = (int*)(er + NN);
  int* cnt    = deg + NN;
  int* rowptr = cnt + NN;
  int* bsum   = rowptr + (NN + 1);
  int* bscan  = bsum + 256;
  int* csr_src = bscan + 256;

  hipMemsetAsync(deg, 0, 2 * NN * sizeof(int), stream);   // deg + cnt (adjacent)
  // wsplit || hist
  fused_pre<<<WSBLK + HBLK, 256, 0, stream>>>(W[0], W[1], W[2], Wh3, Wl3, dst, deg);
  block_sums<<<NB, 256, 0, stream>>>(deg, bsum);
  scan_partials<<<1, 256, 0, stream>>>(bsum, bscan, rowptr);
  scan_final<<<NB, 256, 0, stream>>>(deg, bscan, rowptr);
  // gemm layer 0 || scatter
  fused_scatter_gemm<<<GBLK + HBLK, 256, 0, stream>>>(f, Wh3, Wl3, al[0], ar[0],
                                                      zbuf, el, er,
                                                      src, dst, rowptr, cnt, csr_src);
  gat_agg<<<(NN * 64) / 256, 256, 0, stream>>>(rowptr, csr_src, el, er, zbuf, bb[0], hbuf);

  const float* x = hbuf;
  for (int L = 1; L < 3; L++) {
    float* out = (L == 2) ? (float*)d_out : hbuf;
    gemm_mfma<<<GBLK, 256, 0, stream>>>(x, Wh3 + L * 16384, Wl3 + L * 16384,
                                        al[L], ar[L], zbuf, el, er);
    gat_agg<<<(NN * 64) / 256, 256, 0, stream>>>(rowptr, csr_src, el, er, zbuf, bb[L], out);
    x = out;
  }
}

// Round 8
// 357.163 us; speedup vs baseline: 6.9047x; 1.0625x over previous
//
#include <hip/hip_runtime.h>
#include <math.h>

#define NN 50000
#define NE 800000
#define DD 128
#define NEG_SLOPE 0.2f
#define NB ((NN + 255) / 256)     // 196 scan blocks
#define GBLK ((NN + 127) / 128)   // 391 gemm blocks (128 rows/block, 16/wave, 8 waves)
#define WSBLK (3 * 16384 / 256)   // 192 wsplit blocks
#define HBLK ((NE + 255) / 256)   // 3125 hist blocks (256-thread)
#define SBLK ((NE + 511) / 512)   // 1563 scatter blocks (512-thread)

typedef short frag8 __attribute__((ext_vector_type(8)));
typedef float f32x4 __attribute__((ext_vector_type(4)));

// round-to-nearest-even fp32 -> bf16 (as ushort)
__device__ __forceinline__ unsigned bf16_rne(float x) {
  unsigned u = __float_as_uint(x);
  return (u + 0x7FFFu + ((u >> 16) & 1u)) >> 16;
}

// ---- wsplit body: W pre-split + pre-swizzle into MFMA B-fragment order ----
__device__ __forceinline__ void wsplit_body(
    int bid, const float* __restrict__ W0, const float* __restrict__ W1,
    const float* __restrict__ W2, short* __restrict__ Wh, short* __restrict__ Wl) {
  int gidx = bid * 256 + threadIdx.x;                 // 0..49151
  int L = gidx >> 14;
  int idx = gidx & 16383;
  const float* W = (L == 0) ? W0 : (L == 1) ? W1 : W2;
  int j = idx & 7;
  int lane = (idx >> 3) & 63;
  int tile = idx >> 9;                                // kt*8 + nt
  int nt = tile & 7, kt = tile >> 3;
  int k = kt * 32 + (lane >> 4) * 8 + j;
  int n = nt * 16 + (lane & 15);
  float x = W[k * DD + n];
  unsigned hu = bf16_rne(x);
  float hf = __uint_as_float(hu << 16);
  unsigned lu = bf16_rne(x - hf);
  Wh[gidx] = (short)hu;
  Wl[gidx] = (short)lu;
}

// hist + slot capture: deg count AND per-edge slot within its dst bucket
__device__ __forceinline__ void hist_body(int bid, const int* __restrict__ dst,
                                          int* __restrict__ deg, int* __restrict__ edge_slot) {
  int i = bid * 256 + threadIdx.x;
  if (i < NE) edge_slot[i] = atomicAdd(&deg[dst[i]], 1);
}

// fused: wsplit (192 blocks) || hist (3125 blocks) — both depend only on inputs
__global__ __launch_bounds__(256) void fused_pre(
    const float* __restrict__ W0, const float* __restrict__ W1, const float* __restrict__ W2,
    short* __restrict__ Wh, short* __restrict__ Wl,
    const int* __restrict__ dst, int* __restrict__ deg, int* __restrict__ edge_slot) {
  if (blockIdx.x < WSBLK) wsplit_body(blockIdx.x, W0, W1, W2, Wh, Wl);
  else hist_body(blockIdx.x - WSBLK, dst, deg, edge_slot);
}

// ---- GEMM body: z = x@W via split-bf16 MFMA. 8-wave (512-thread) block, 128 rows,
// B shared via double-buffered 32 KB LDS. Fused el = z.al, er = z.ar. ----
__device__ __forceinline__ void gemm_body(
    int bid, short (*sB)[8192],
    const float* __restrict__ x, const short* __restrict__ Wh, const short* __restrict__ Wl,
    const float* __restrict__ al, const float* __restrict__ ar,
    float* __restrict__ z, float* __restrict__ el, float* __restrict__ er) {
  const int t = threadIdx.x;
  const int w = t >> 6, lane = t & 63;
  const int m = lane & 15, quad = lane >> 4;
  const int R0 = bid * 128 + w * 16;

  auto stage = [&](int kt, int buf) {
    const uint4* gh = (const uint4*)(Wh + kt * 4096);   // 512 uint4 (8 KB)
    const uint4* gl = (const uint4*)(Wl + kt * 4096);
    uint4* s = (uint4*)sB[buf];                         // 1024 uint4 (16 KB)
    s[t] = gh[t];
    s[t + 512] = gl[t];
  };

  f32x4 acc[8];
#pragma unroll
  for (int nt = 0; nt < 8; nt++) acc[nt] = (f32x4)(0.f);

  int rA = R0 + m; if (rA > NN - 1) rA = NN - 1;  // clamp OOB rows; stores guarded

  stage(0, 0);
  __syncthreads();

#pragma unroll
  for (int kt = 0; kt < 4; kt++) {
    const int buf = kt & 1;
    if (kt < 3) stage(kt + 1, buf ^ 1);

    const float* xp = x + (size_t)rA * DD + kt * 32 + quad * 8;
    float xv[8];
    *(float4*)(xv) = *(const float4*)xp;
    *(float4*)(xv + 4) = *(const float4*)(xp + 4);
    frag8 ah, alo;
#pragma unroll
    for (int j = 0; j < 8; j++) {
      unsigned hu = bf16_rne(xv[j]);
      float hf = __uint_as_float(hu << 16);
      ah[j] = (short)hu;
      alo[j] = (short)bf16_rne(xv[j] - hf);
    }
#pragma unroll
    for (int nt = 0; nt < 8; nt++) {
      frag8 bh = *(const frag8*)&sB[buf][nt * 512 + lane * 8];
      frag8 bl = *(const frag8*)&sB[buf][4096 + nt * 512 + lane * 8];
      acc[nt] = __builtin_amdgcn_mfma_f32_16x16x32_bf16(alo, bh, acc[nt], 0, 0, 0);
      acc[nt] = __builtin_amdgcn_mfma_f32_16x16x32_bf16(ah, bl, acc[nt], 0, 0, 0);
      acc[nt] = __builtin_amdgcn_mfma_f32_16x16x32_bf16(ah, bh, acc[nt], 0, 0, 0);
    }
    __syncthreads();
  }

  float alv[8], arv[8];
#pragma unroll
  for (int nt = 0; nt < 8; nt++) { alv[nt] = al[nt * 16 + m]; arv[nt] = ar[nt * 16 + m]; }
#pragma unroll
  for (int r = 0; r < 4; r++) {
    float pl = 0.f, pr = 0.f;
#pragma unroll
    for (int nt = 0; nt < 8; nt++) { pl += acc[nt][r] * alv[nt]; pr += acc[nt][r] * arv[nt]; }
#pragma unroll
    for (int off = 8; off; off >>= 1) {
      pl += __shfl_xor(pl, off, 64);
      pr += __shfl_xor(pr, off, 64);
    }
    int row = R0 + quad * 4 + r;
    if (row < NN) {
      if (m == 0) { el[row] = pl; er[row] = pr; }
#pragma unroll
      for (int nt = 0; nt < 8; nt++) z[(size_t)row * DD + nt * 16 + m] = acc[nt][r];
    }
  }
}

// atomic-free scatter: position = rowptr[dst] + precomputed slot
__device__ __forceinline__ void scatter_body(
    int bid, const int* __restrict__ src, const int* __restrict__ dst,
    const int* __restrict__ rowptr, const int* __restrict__ edge_slot,
    int* __restrict__ csr_src) {
  int i = bid * 512 + threadIdx.x;
  if (i >= NE) return;
  csr_src[rowptr[dst[i]] + edge_slot[i]] = src[i];
}

// standalone gemm for layers 1,2
__global__ __launch_bounds__(512) void gemm_mfma(
    const float* __restrict__ x, const short* __restrict__ Wh, const short* __restrict__ Wl,
    const float* __restrict__ al, const float* __restrict__ ar,
    float* __restrict__ z, float* __restrict__ el, float* __restrict__ er) {
  __shared__ __align__(16) short sB[2][8192];
  gemm_body(blockIdx.x, sB, x, Wh, Wl, al, ar, z, el, er);
}

// fused: gemm0 (391 blocks, scheduled first) || scatter (1563 blocks)
__global__ __launch_bounds__(512) void fused_scatter_gemm(
    const float* __restrict__ x, const short* __restrict__ Wh, const short* __restrict__ Wl,
    const float* __restrict__ al, const float* __restrict__ ar,
    float* __restrict__ z, float* __restrict__ el, float* __restrict__ er,
    const int* __restrict__ src, const int* __restrict__ dst,
    const int* __restrict__ rowptr, const int* __restrict__ edge_slot,
    int* __restrict__ csr_src) {
  __shared__ __align__(16) short sB[2][8192];
  if (blockIdx.x < GBLK) gemm_body(blockIdx.x, sB, x, Wh, Wl, al, ar, z, el, er);
  else scatter_body(blockIdx.x - GBLK, src, dst, rowptr, edge_slot, csr_src);
}

// ---- scan kernels ----
__global__ __launch_bounds__(256) void block_sums(const int* __restrict__ deg, int* __restrict__ bsum) {
  int i = blockIdx.x * 256 + threadIdx.x;
  int v = (i < NN) ? deg[i] : 0;
#pragma unroll
  for (int off = 32; off; off >>= 1) v += __shfl_xor(v, off, 64);
  __shared__ int wsum[4];
  if ((threadIdx.x & 63) == 0) wsum[threadIdx.x >> 6] = v;
  __syncthreads();
  if (threadIdx.x == 0) bsum[blockIdx.x] = wsum[0] + wsum[1] + wsum[2] + wsum[3];
}

__global__ __launch_bounds__(256) void scan_partials(const int* __restrict__ bsum,
                                                     int* __restrict__ bscan, int* __restrict__ rowptr) {
  __shared__ int sh[256];
  int t = threadIdx.x;
  int v = (t < NB) ? bsum[t] : 0;
  sh[t] = v;
  __syncthreads();
  for (int off = 1; off < 256; off <<= 1) {
    int u = (t >= off) ? sh[t - off] : 0;
    __syncthreads();
    sh[t] += u;
    __syncthreads();
  }
  bscan[t] = sh[t] - v;
  if (t == 255) rowptr[NN] = sh[255];
}

__global__ __launch_bounds__(256) void scan_final(const int* __restrict__ deg,
                                                  const int* __restrict__ bscan, int* __restrict__ rowptr) {
  __shared__ int sh[256];
  int t = threadIdx.x;
  int i = blockIdx.x * 256 + t;
  int v = (i < NN) ? deg[i] : 0;
  sh[t] = v;
  __syncthreads();
  for (int off = 1; off < 256; off <<= 1) {
    int u = (t >= off) ? sh[t - off] : 0;
    __syncthreads();
    sh[t] += u;
    __syncthreads();
  }
  if (i < NN) rowptr[i] = bscan[blockIdx.x] + sh[t] - v;
}

// ---- Fused softmax + aggregation + bias + ReLU. One wave per node, unroll 8. ----
__global__ __launch_bounds__(256) void gat_agg(
    const int* __restrict__ rowptr, const int* __restrict__ csr_src,
    const float* __restrict__ el, const float* __restrict__ er,
    const float* __restrict__ z, const float* __restrict__ b,
    float* __restrict__ out) {
  int node = (int)((blockIdx.x * 256 + threadIdx.x) >> 6);
  int lane = threadIdx.x & 63;
  if (node >= NN) return;
  int beg = rowptr[node], end = rowptr[node + 1];
  float erd = er[node];
  const float* zb = z + lane * 2;

  float2 acc = make_float2(0.f, 0.f);
  float ssum = 0.f;
  for (int base = beg; base < end; base += 64) {
    int j = base + lane;
    int sn = 0; float w = 0.f;
    if (j < end) {
      sn = csr_src[j];
      float e = el[sn] + erd;
      e = (e > 0.f) ? e : NEG_SLOPE * e;
      w = __expf(e);
    }
    ssum += w;
    int cnt = min(64, end - base);
    int jj = 0;
    for (; jj + 8 <= cnt; jj += 8) {
      float ww[8]; int ss[8];
#pragma unroll
      for (int u = 0; u < 8; u++) {
        ww[u] = __shfl(w, jj + u, 64);
        ss[u] = __shfl(sn, jj + u, 64);
      }
      float2 zv[8];
#pragma unroll
      for (int u = 0; u < 8; u++) zv[u] = *(const float2*)(zb + (size_t)ss[u] * DD);
#pragma unroll
      for (int u = 0; u < 8; u++) { acc.x += ww[u] * zv[u].x; acc.y += ww[u] * zv[u].y; }
    }
    for (; jj < cnt; jj++) {
      float wj = __shfl(w, jj, 64);
      int snj = __shfl(sn, jj, 64);
      float2 zv = *(const float2*)(zb + (size_t)snj * DD);
      acc.x += wj * zv.x; acc.y += wj * zv.y;
    }
  }
#pragma unroll
  for (int off = 32; off; off >>= 1) ssum += __shfl_xor(ssum, off, 64);
  float inv_s = (end > beg) ? 1.f / ssum : 0.f;

  float2 bv = *(const float2*)(b + lane * 2);
  float ox = acc.x * inv_s + bv.x, oy = acc.y * inv_s + bv.y;
  *(float2*)(out + (size_t)node * DD + lane * 2) = make_float2(ox > 0.f ? ox : 0.f, oy > 0.f ? oy : 0.f);
}

extern "C" void kernel_launch(void* const* d_in, const int* in_sizes, int n_in,
                              void* d_out, int out_size, void* d_ws, size_t ws_size,
                              hipStream_t stream) {
  const float* f   = (const float*)d_in[0];
  const int*   src = (const int*)d_in[1];
  const int*   dst = (const int*)d_in[2];
  const float* W[3]  = {(const float*)d_in[3], (const float*)d_in[7],  (const float*)d_in[11]};
  const float* al[3] = {(const float*)d_in[4], (const float*)d_in[8],  (const float*)d_in[12]};
  const float* ar[3] = {(const float*)d_in[5], (const float*)d_in[9],  (const float*)d_in[13]};
  const float* bb[3] = {(const float*)d_in[6], (const float*)d_in[10], (const float*)d_in[14]};

  // ws layout: Wh[3] | Wl[3] (shorts) | z | h | el | er (floats) | deg | rowptr | bsum | bscan | edge_slot | csr_src
  short* Wh3 = (short*)d_ws;                 // 3 * 16384 shorts
  short* Wl3 = Wh3 + 3 * 16384;
  float* zbuf = (float*)(Wl3 + 3 * 16384);
  float* hbuf = zbuf + (size_t)NN * DD;
  float* el   = hbuf + (size_t)NN * DD;
  float* er   = el + NN;
  int* deg      = (int*)(er + NN);
  int* rowptr   = deg + NN;
  int* bsum     = rowptr + (NN + 1);
  int* bscan    = bsum + 256;
  int* edge_slot = bscan + 256;
  int* csr_src   = edge_slot + NE;

  hipMemsetAsync(deg, 0, NN * sizeof(int), stream);
  // wsplit || (hist + slot capture)
  fused_pre<<<WSBLK + HBLK, 256, 0, stream>>>(W[0], W[1], W[2], Wh3, Wl3, dst, deg, edge_slot);
  block_sums<<<NB, 256, 0, stream>>>(deg, bsum);
  scan_partials<<<1, 256, 0, stream>>>(bsum, bscan, rowptr);
  scan_final<<<NB, 256, 0, stream>>>(deg, bscan, rowptr);
  // gemm layer 0 || atomic-free scatter
  fused_scatter_gemm<<<GBLK + SBLK, 512, 0, stream>>>(f, Wh3, Wl3, al[0], ar[0],
                                                      zbuf, el, er,
                                                      src, dst, rowptr, edge_slot, csr_src);
  gat_agg<<<(NN * 64) / 256, 256, 0, stream>>>(rowptr, csr_src, el, er, zbuf, bb[0], hbuf);

  const float* x = hbuf;
  for (int L = 1; L < 3; L++) {
    float* out = (L == 2) ? (float*)d_out : hbuf;
    gemm_mfma<<<GBLK, 512, 0, stream>>>(x, Wh3 + L * 16384, Wl3 + L * 16384,
                                        al[L], ar[L], zbuf, el, er);
    gat_agg<<<(NN * 64) / 256, 256, 0, stream>>>(rowptr, csr_src, el, er, zbuf, bb[L], out);
    x = out;
  }
}